// Round 10
// baseline (346.021 us; speedup 1.0000x reference)
//
#include <hip/hip_runtime.h>
#include <math.h>

// Problem constants
constexpr int ROWS  = 19456;   // B*C*N = 16*19*64
constexpr int IN_DIM = 200;
constexpr int FREQ  = 101;     // rfft bins
constexpr int VQD   = 64;
constexpr int NEMB  = 8192;

typedef __attribute__((ext_vector_type(8))) short short8;   // 8 bf16 = 4 VGPRs
typedef __attribute__((ext_vector_type(4))) float floatx4;

__device__ __forceinline__ unsigned short f2bf(float v) {   // RTN-even fp32->bf16
    unsigned int u = __builtin_bit_cast(unsigned int, v);
    unsigned int r = u + 0x7fffu + ((u >> 16) & 1u);
    return (unsigned short)(r >> 16);
}
__device__ __forceinline__ float bf2f(unsigned short b) {
    unsigned int u = ((unsigned int)b) << 16;
    return __builtin_bit_cast(float, u);
}

// async global->LDS DMA, 16 B per lane; LDS dest = wave-uniform base + lane*16
#define GLOAD_LDS(gp, lp) __builtin_amdgcn_global_load_lds( \
    (const __attribute__((address_space(1))) unsigned int*)(gp), \
    (__attribute__((address_space(3))) unsigned int*)(lp), 16, 0, 0)

// ---------------- workspace layout ----------------
constexpr size_t align256(size_t x) { return (x + 255) & ~(size_t)255; }
constexpr size_t SZ_FB    = (size_t)2 * ROWS * VQD * sizeof(unsigned short); // bf16 feats [2][ROWS][64]
constexpr size_t OFF_FTH  = 0;
constexpr size_t OFF_FTL  = align256(OFF_FTH + SZ_FB);
constexpr size_t SZ_CBB   = (size_t)2 * NEMB * VQD * sizeof(unsigned short); // bf16 codes [2][8192][64]
constexpr size_t OFF_CBH  = align256(OFF_FTL + SZ_FB);
constexpr size_t OFF_CBL  = align256(OFF_CBH + SZ_CBB);
constexpr size_t SZ_FD    = (size_t)2 * ROWS * VQD * sizeof(double);         // f64 feats
constexpr size_t OFF_FD   = align256(OFF_CBL + SZ_CBB);
constexpr size_t SZ_INV   = (size_t)2 * NEMB * sizeof(double);               // f64 1/||cb||
constexpr size_t OFF_INV  = align256(OFF_FD + SZ_FD);
constexpr size_t SZ_PI    = (size_t)2 * 4 * ROWS * sizeof(int);              // top-2 per 2048-chunk
constexpr size_t OFF_PI1  = align256(OFF_INV + SZ_INV);
constexpr size_t OFF_PI2  = align256(OFF_PI1 + SZ_PI);

// ---------------- 1. DFT + amp/phase + projection (f64), 8 rows per block ----------------
// (validated rounds 5-9; fused twiddle via per-lane complex rotation recurrence)
__global__ __launch_bounds__(128, 4) void dft_proj_kernel(
    const float* __restrict__ x, const float* __restrict__ projA, const float* __restrict__ projP,
    unsigned short* __restrict__ ftH, unsigned short* __restrict__ ftL, double* __restrict__ featD)
{
    __shared__ __align__(16) float  xsT[IN_DIM * 8];      // [n][r]  6.4 KB
    __shared__ double ampL[8 * FREQ];                     // [r][k]  6.5 KB
    __shared__ double phL [8 * FREQ];                     //         6.5 KB
    const int tid = threadIdx.x;
    const int r0 = blockIdx.x * 8;

    for (int e = tid; e < 8 * IN_DIM; e += 128) {
        int r = e / IN_DIM, n = e - r * IN_DIM;
        xsT[n * 8 + r] = x[(size_t)(r0 + r) * IN_DIM + n];
    }
    __syncthreads();

    const int k = tid;
    if (k < FREQ) {
        double c1, s1;
        if (k == 0)        { c1 =  1.0; s1 =  0.0; }
        else if (k == 50)  { c1 =  0.0; s1 = -1.0; }
        else if (k == 100) { c1 = -1.0; s1 =  0.0; }
        else {
            double ang = -6.283185307179586476925286766559 * (double)k / (double)IN_DIM;
            c1 = cos(ang); s1 = sin(ang);
        }
        double wc = 1.0, ws = 0.0;
        double re[8], im[8];
#pragma unroll
        for (int r = 0; r < 8; ++r) { re[r] = 0.0; im[r] = 0.0; }

        for (int n = 0; n < IN_DIM; ++n) {
            const float4* xp = (const float4*)(xsT + n * 8);
            float4 x0 = xp[0], x1 = xp[1];
            float xv[8] = {x0.x, x0.y, x0.z, x0.w, x1.x, x1.y, x1.z, x1.w};
#pragma unroll
            for (int r = 0; r < 8; ++r) {
                double xd = (double)xv[r];
                re[r] = fma(xd, wc, re[r]);
                im[r] = fma(xd, ws, im[r]);
            }
            double nwc = wc * c1 - ws * s1;
            double nws = wc * s1 + ws * c1;
            wc = nwc; ws = nws;
        }
#pragma unroll
        for (int r = 0; r < 8; ++r) {
            ampL[r * FREQ + k] = sqrt(re[r] * re[r] + im[r] * im[r]);
            phL [r * FREQ + k] = atan2(im[r], re[r]);
        }
    }
    __syncthreads();

    const int d = tid & 63, which = tid >> 6;
    const float*  proj = which ? projP : projA;
    const double* src  = which ? phL : ampL;
    double acc[8];
#pragma unroll
    for (int r = 0; r < 8; ++r) acc[r] = 0.0;
    for (int kk = 0; kk < FREQ; ++kk) {
        double p = (double)proj[kk * VQD + d];
#pragma unroll
        for (int r = 0; r < 8; ++r) acc[r] += src[r * FREQ + kk] * p;
    }
#pragma unroll
    for (int r = 0; r < 8; ++r) {
        size_t rowi = (size_t)which * ROWS + r0 + r;
        float vf = (float)acc[r];
        unsigned short hb = f2bf(vf);
        unsigned short lb = f2bf(vf - bf2f(hb));
        ftH[rowi * VQD + d] = hb;
        ftL[rowi * VQD + d] = lb;
        featD[rowi * VQD + d] = acc[r];
    }
}

// ---------------- 2. codebook: fold 1/||cb|| + bf16 hi/lo split + f64 inv-norm ----------------
__global__ __launch_bounds__(256) void cb_prep_kernel(
    const float* __restrict__ cbA, const float* __restrict__ cbP,
    unsigned short* __restrict__ cbH, unsigned short* __restrict__ cbL,
    double* __restrict__ invnD)
{
    __shared__ float tile[64 * 65];
    __shared__ float inv[64];
    const int tid = threadIdx.x;
    const int which = blockIdx.y;
    const int m0 = blockIdx.x * 64;
    const float* cb = which ? cbP : cbA;
    for (int e = tid; e < 4096; e += 256) {
        int c = e >> 6, d = e & 63;
        tile[c * 65 + d] = cb[(size_t)(m0 + c) * VQD + d];
    }
    __syncthreads();
    if (tid < 64) {
        double s = 0.0;
        for (int d2 = 0; d2 < 64; ++d2) { double v = (double)tile[tid * 65 + d2]; s += v * v; }
        inv[tid] = (float)(1.0 / sqrt(s));
        invnD[(size_t)which * NEMB + m0 + tid] = 1.0 / sqrt(s);
    }
    __syncthreads();
    for (int e = tid; e < 4096; e += 256) {
        int c = e >> 6, d = e & 63;
        float v = tile[c * 65 + d] * inv[c];
        unsigned short hb = f2bf(v);
        unsigned short lb = f2bf(v - bf2f(hb));
        size_t o = ((size_t)which * NEMB + m0 + c) * VQD + d;
        cbH[o] = hb; cbL[o] = lb;
    }
}

// ---------------- 3. bf16x3 MFMA sim + top-2, DMA double-buffered prefetch ----------------
// Round-9 math/layout (bitwise identical scores) with the K-loop restructured:
// 64-code tiles, two 16-KB LDS buffers, ONE barrier per tile. Per iteration:
//   barrier (drains tile it's DMA - already ~complete, it had the whole previous
//   compute phase to land) -> issue tile it+1's DMA into the other buffer ->
//   compute tile it. This is the "true async prefetch into a separate LDS region"
//   that removes the post-issue barrier drain (the ~600-900 cyc x 16 stall).
// Prefetch costs ZERO VGPRs (DMA goes straight to LDS) - unlike round-7's failed
// register prefetch. LDS stays 33792 B -> occupancy unchanged (4 blocks/CU).
#define MFMA(a, b, c) __builtin_amdgcn_mfma_f32_16x16x32_bf16(a, b, c, 0, 0, 0)
#define UPD(val, s) do { float _v = (val); \
    bool _c1 = _v > b1v[s]; bool _c2 = _v > b2v[s]; \
    b2v[s] = _c1 ? b1v[s] : (_c2 ? _v : b2v[s]); \
    b2i[s] = _c1 ? b1i[s] : (_c2 ? idx : b2i[s]); \
    b1v[s] = _c1 ? _v : b1v[s]; \
    b1i[s] = _c1 ? idx : b1i[s]; } while (0)

__global__ __launch_bounds__(256, 3) void argmax_kernel(
    const unsigned short* __restrict__ ftH, const unsigned short* __restrict__ ftL,
    const unsigned short* __restrict__ cbH, const unsigned short* __restrict__ cbL,
    int* __restrict__ pi1, int* __restrict__ pi2)
{
    // two 16384-B tile buffers (H 0..8191, L 8192..16383 within each);
    // reduction scratch (33792 B) reuses the whole range after the loop
    __shared__ __align__(16) char lds[33792];
    const int tid = threadIdx.x;
    const int f = blockIdx.y, z = blockIdx.z;
    const int r0 = blockIdx.x * 128;
    const int w = tid >> 6, lane = tid & 63;
    const int q = lane >> 4, cl = lane & 15;

    const unsigned short* ftHb = ftH + (size_t)f * ROWS * VQD;
    const unsigned short* ftLb = ftL + (size_t)f * ROWS * VQD;
    const unsigned short* cbHb = cbH + (size_t)f * NEMB * VQD;
    const unsigned short* cbLb = cbL + (size_t)f * NEMB * VQD;

    // A fragments: rows r0 + w*32 + {cl, 16+cl}; per-lane k = kb*32 + q*8 .. +8
    short8 aH00, aH01, aH10, aH11, aL00, aL01, aL10, aL11;
    {
        const size_t baseA = (size_t)(r0 + w * 32 + cl) * VQD + q * 8;
        const size_t baseB = baseA + (size_t)16 * VQD;
        aH00 = *(const short8*)(ftHb + baseA);
        aH01 = *(const short8*)(ftHb + baseA + 32);
        aH10 = *(const short8*)(ftHb + baseB);
        aH11 = *(const short8*)(ftHb + baseB + 32);
        aL00 = *(const short8*)(ftLb + baseA);
        aL01 = *(const short8*)(ftLb + baseA + 32);
        aL10 = *(const short8*)(ftLb + baseB);
        aL11 = *(const short8*)(ftLb + baseB + 32);
    }

    float b1v[8], b2v[8]; int b1i[8], b2i[8];
#pragma unroll
    for (int s = 0; s < 8; ++s) { b1v[s] = -INFINITY; b2v[s] = -INFINITY; b1i[s] = 0; b2i[s] = 0; }

    // staging source (round-9 validated XOR swizzle, bank behavior unchanged):
    // thread -> codeBase = tid>>3 (+32 per DMA round), chunk j = (tid&7)^(codeBase&7)
    const int cBase = tid >> 3;
    const int jel   = (((tid & 7) ^ (cBase & 7)) << 3);
    const unsigned short* gH = cbHb + (size_t)(z * 2048 + cBase) * VQD + jel;
    const unsigned short* gL = cbLb + (size_t)(z * 2048 + cBase) * VQD + jel;

    // swizzled B-read offsets (chunks q and q+4 of code nt*16+cl)
    const int p0 = ((q ^ (cl & 7)) << 4);
    const int p1 = p0 ^ 64;

    // prologue: stage tile 0 into buffer 0 (64 codes = 2 DMA rounds each for H and L)
#pragma unroll
    for (int r = 0; r < 2; ++r) {
        const size_t gofs = (size_t)(32 * r) * VQD;
        GLOAD_LDS(gH + gofs, lds + w * 1024 + r * 4096);
        GLOAD_LDS(gL + gofs, lds + 8192 + w * 1024 + r * 4096);
    }

    for (int it = 0; it < 32; ++it) {
        __syncthreads();   // drains tile it's DMA (already landed) + seals buffer recycling
        if (it < 31) {     // prefetch tile it+1 into the other buffer; latency hides under compute
            char* nbuf = lds + ((it + 1) & 1) * 16384;
            const size_t gbase = (size_t)((it + 1) * 64) * VQD;
#pragma unroll
            for (int r = 0; r < 2; ++r) {
                const size_t gofs = gbase + (size_t)(32 * r) * VQD;
                GLOAD_LDS(gH + gofs, nbuf + w * 1024 + r * 4096);
                GLOAD_LDS(gL + gofs, nbuf + 8192 + w * 1024 + r * 4096);
            }
        }

        const char* buf = lds + (it & 1) * 16384;
        const int cbase = z * 2048 + it * 64;
#pragma unroll
        for (int nt = 0; nt < 4; ++nt) {
            const char* row = buf + (nt * 16 + cl) * 128;
            short8 bH0 = *(const short8*)(row + p0);
            short8 bH1 = *(const short8*)(row + p1);
            short8 bL0 = *(const short8*)(row + 8192 + p0);
            short8 bL1 = *(const short8*)(row + 8192 + p1);

            floatx4 acc0 = {0.f, 0.f, 0.f, 0.f};
            floatx4 acc1 = {0.f, 0.f, 0.f, 0.f};
            acc0 = MFMA(aH00, bH0, acc0);  acc1 = MFMA(aH10, bH0, acc1);
            acc0 = MFMA(aH01, bH1, acc0);  acc1 = MFMA(aH11, bH1, acc1);
            acc0 = MFMA(aH00, bL0, acc0);  acc1 = MFMA(aH10, bL0, acc1);
            acc0 = MFMA(aH01, bL1, acc0);  acc1 = MFMA(aH11, bL1, acc1);
            acc0 = MFMA(aL00, bH0, acc0);  acc1 = MFMA(aL10, bH0, acc1);
            acc0 = MFMA(aL01, bH1, acc0);  acc1 = MFMA(aL11, bH1, acc1);

            const int idx = cbase + nt * 16 + cl;
#pragma unroll
            for (int i = 0; i < 4; ++i) { UPD(acc0[i], i); UPD(acc1[i], 4 + i); }
        }
    }

    // block reduction: per-lane top-2 (col-slice cl) -> per-row top-2 of 2048
    __syncthreads();
    float* redv = (float*)lds;           // [128][33]
    int*   redi = (int*)(lds + 128 * 33 * 4);
#pragma unroll
    for (int s = 0; s < 8; ++s) {
        int rowl = w * 32 + ((s & 4) << 2) + q * 4 + (s & 3);   // +16 when s>=4
        int base = rowl * 33 + cl * 2;
        redv[base]     = b1v[s]; redi[base]     = b1i[s];
        redv[base + 1] = b2v[s]; redi[base + 1] = b2i[s];
    }
    __syncthreads();
    if (tid < 128) {
        float v1 = -INFINITY, v2 = -INFINITY; int i1 = 0x7fffffff, i2 = 0x7fffffff;
        for (int e = 0; e < 32; ++e) {
            float v = redv[tid * 33 + e]; int id = redi[tid * 33 + e];
            if (v > v1 || (v == v1 && id < i1)) { v2 = v1; i2 = i1; v1 = v; i1 = id; }
            else if (v > v2 || (v == v2 && id < i2)) { v2 = v; i2 = id; }
        }
        size_t p = ((size_t)(f * 4 + z)) * ROWS + r0 + tid;
        pi1[p] = i1; pi2[p] = i2;
    }
}

// ---------------- 4. f64 rescore of the 8 candidates/row (round-5 version) ----------------
__global__ __launch_bounds__(256) void rescore_kernel(
    const double* __restrict__ featD, const double* __restrict__ invnD,
    const float* __restrict__ cbA, const float* __restrict__ cbP,
    const int* __restrict__ pi1, const int* __restrict__ pi2,
    int* __restrict__ out)
{
    const int tid = threadIdx.x;
    const int lane = tid & 63, wave = tid >> 6;
    const int task = blockIdx.x * 4 + wave;           // 0 .. 2*ROWS-1
    const int f = task / ROWS;
    const int row = task - f * ROWS;
    const float* cb = f ? cbP : cbA;
    const double fd = featD[((size_t)f * ROWS + row) * VQD + lane];

    int idxs[8];
#pragma unroll
    for (int c = 0; c < 8; ++c) {
        int zz = c >> 1;
        size_t p = ((size_t)(f * 4 + zz)) * ROWS + row;
        idxs[c] = (c & 1) ? pi2[p] : pi1[p];
    }
    double cv[8];
#pragma unroll
    for (int c = 0; c < 8; ++c)
        cv[c] = (double)cb[(size_t)idxs[c] * VQD + lane];

    double bestv = -1.0e300; int besti = 0x7fffffff;
#pragma unroll
    for (int c = 0; c < 8; ++c) {
        double t = fd * cv[c];
        for (int m = 32; m >= 1; m >>= 1) t += __shfl_xor(t, m, 64);
        double sim = t * invnD[(size_t)f * NEMB + idxs[c]];
        int idx = idxs[c];
        if (sim > bestv || (sim == bestv && idx < besti)) { bestv = sim; besti = idx; }
    }
    if (lane == 0) out[task] = besti;
}

// ---------------- launch ----------------
extern "C" void kernel_launch(void* const* d_in, const int* in_sizes, int n_in,
                              void* d_out, int out_size, void* d_ws, size_t ws_size,
                              hipStream_t stream)
{
    const float* x     = (const float*)d_in[0];
    const float* projA = (const float*)d_in[1];
    const float* projP = (const float*)d_in[2];
    const float* cbA   = (const float*)d_in[3];
    const float* cbP   = (const float*)d_in[4];

    char* ws = (char*)d_ws;
    unsigned short* ftH   = (unsigned short*)(ws + OFF_FTH);
    unsigned short* ftL   = (unsigned short*)(ws + OFF_FTL);
    unsigned short* cbHp  = (unsigned short*)(ws + OFF_CBH);
    unsigned short* cbLp  = (unsigned short*)(ws + OFF_CBL);
    double*         featD = (double*)(ws + OFF_FD);
    double*         invnD = (double*)(ws + OFF_INV);
    int*            pi1   = (int*)(ws + OFF_PI1);
    int*            pi2   = (int*)(ws + OFF_PI2);

    dft_proj_kernel<<<ROWS / 8, 128, 0, stream>>>(x, projA, projP, ftH, ftL, featD);
    cb_prep_kernel<<<dim3(NEMB / 64, 2), 256, 0, stream>>>(cbA, cbP, cbHp, cbLp, invnD);
    argmax_kernel<<<dim3(ROWS / 128, 2, 4), 256, 0, stream>>>(ftH, ftL, cbHp, cbLp, pi1, pi2);
    rescore_kernel<<<(2 * ROWS) / 4, 256, 0, stream>>>(featD, invnD, cbA, cbP, pi1, pi2, (int*)d_out);
}

// Round 11
// 325.127 us; speedup vs baseline: 1.0643x; 1.0643x over previous
//
#include <hip/hip_runtime.h>
#include <math.h>

// Problem constants
constexpr int ROWS  = 19456;   // B*C*N = 16*19*64
constexpr int IN_DIM = 200;
constexpr int FREQ  = 101;     // rfft bins
constexpr int VQD   = 64;
constexpr int NEMB  = 8192;
constexpr int DFT_BLOCKS = ROWS / 8;   // 2432

typedef __attribute__((ext_vector_type(8))) short short8;   // 8 bf16 = 4 VGPRs
typedef __attribute__((ext_vector_type(4))) float floatx4;

__device__ __forceinline__ unsigned short f2bf(float v) {   // RTN-even fp32->bf16
    unsigned int u = __builtin_bit_cast(unsigned int, v);
    unsigned int r = u + 0x7fffu + ((u >> 16) & 1u);
    return (unsigned short)(r >> 16);
}
__device__ __forceinline__ float bf2f(unsigned short b) {
    unsigned int u = ((unsigned int)b) << 16;
    return __builtin_bit_cast(float, u);
}

// async global->LDS DMA, 16 B per lane; LDS dest = wave-uniform base + lane*16
#define GLOAD_LDS(gp, lp) __builtin_amdgcn_global_load_lds( \
    (const __attribute__((address_space(1))) unsigned int*)(gp), \
    (__attribute__((address_space(3))) unsigned int*)(lp), 16, 0, 0)

// ---------------- workspace layout ----------------
constexpr size_t align256(size_t x) { return (x + 255) & ~(size_t)255; }
constexpr size_t SZ_FB    = (size_t)2 * ROWS * VQD * sizeof(unsigned short); // bf16 feats [2][ROWS][64]
constexpr size_t OFF_FTH  = 0;
constexpr size_t OFF_FTL  = align256(OFF_FTH + SZ_FB);
constexpr size_t SZ_CBB   = (size_t)2 * NEMB * VQD * sizeof(unsigned short); // bf16 codes [2][8192][64]
constexpr size_t OFF_CBH  = align256(OFF_FTL + SZ_FB);
constexpr size_t OFF_CBL  = align256(OFF_CBH + SZ_CBB);
constexpr size_t SZ_FD    = (size_t)2 * ROWS * VQD * sizeof(double);         // f64 feats
constexpr size_t OFF_FD   = align256(OFF_CBL + SZ_CBB);
constexpr size_t SZ_INV   = (size_t)2 * NEMB * sizeof(double);               // f64 1/||cb||
constexpr size_t OFF_INV  = align256(OFF_FD + SZ_FD);
constexpr size_t SZ_PI    = (size_t)2 * 4 * ROWS * sizeof(int);              // top-2 per 2048-chunk
constexpr size_t OFF_PI1  = align256(OFF_INV + SZ_INV);
constexpr size_t OFF_PI2  = align256(OFF_PI1 + SZ_PI);

// ---------------- 1. fused DFT/proj (blocks < 2432) + cb_prep (blocks >= 2432) ----------------
// DFT: 8 rows/block, 256 threads. n-loop split across thread-halves: half 1 starts at
// n=100 with the EXACT twiddle cis(-pi k) = ((-1)^k, +0) -- signed-zero accumulation for
// k=0/100 unchanged (im stays +0, atan2(+0, re<0) = +pi matches numpy). Partial (re,im)
// and projection kk-split partials combine via LDS; the f64 reorder is ~1e-16 relative,
// far inside the ~2e-14 perturbation already validated (table->recurrence switch, r3->r4).
__global__ __launch_bounds__(256) void dft_cb_kernel(
    const float* __restrict__ x, const float* __restrict__ projA, const float* __restrict__ projP,
    const float* __restrict__ cbA, const float* __restrict__ cbP,
    unsigned short* __restrict__ ftH, unsigned short* __restrict__ ftL, double* __restrict__ featD,
    unsigned short* __restrict__ cbH, unsigned short* __restrict__ cbL, double* __restrict__ invnD)
{
    __shared__ __align__(16) char smem[21120];
    const int tid = threadIdx.x;

    if (blockIdx.x >= DFT_BLOCKS) {
        // ---- cb_prep body (validated rounds 5-10) ----
        float* tile = (float*)smem;            // 64*65*4 = 16640 B
        float* inv  = (float*)(smem + 16640);  // 256 B
        const int bid2 = blockIdx.x - DFT_BLOCKS;
        const int which = bid2 >> 7;
        const int m0 = (bid2 & 127) * 64;
        const float* cb = which ? cbP : cbA;
        for (int e = tid; e < 4096; e += 256) {
            int c = e >> 6, d = e & 63;
            tile[c * 65 + d] = cb[(size_t)(m0 + c) * VQD + d];
        }
        __syncthreads();
        if (tid < 64) {
            double s = 0.0;
            for (int d2 = 0; d2 < 64; ++d2) { double v = (double)tile[tid * 65 + d2]; s += v * v; }
            inv[tid] = (float)(1.0 / sqrt(s));
            invnD[(size_t)which * NEMB + m0 + tid] = 1.0 / sqrt(s);
        }
        __syncthreads();
        for (int e = tid; e < 4096; e += 256) {
            int c = e >> 6, d = e & 63;
            float v = tile[c * 65 + d] * inv[c];
            unsigned short hb = f2bf(v);
            unsigned short lb = f2bf(v - bf2f(hb));
            size_t o = ((size_t)which * NEMB + m0 + c) * VQD + d;
            cbH[o] = hb; cbL[o] = lb;
        }
        return;
    }

    // ---- DFT + amp/phase + projection ----
    float*  xsT  = (float*)smem;                    // [n][r] 6400 B (region reused for proj partials)
    double* reS  = (double*)(smem + 8192);          // [k][r] 6464 B: half-1 partials, then amp
    double* imS  = (double*)(smem + 8192 + 6464);   // [k][r] 6464 B: half-1 partials, then phase
    double* accS = (double*)smem;                   // proj partials (8192 B), after xsT is dead
    const int r0 = blockIdx.x * 8;

    for (int e = tid; e < 8 * IN_DIM; e += 256) {
        int r = e / IN_DIM, n = e - r * IN_DIM;
        xsT[n * 8 + r] = x[(size_t)(r0 + r) * IN_DIM + n];
    }
    __syncthreads();

    const int k = tid & 127, half = tid >> 7;
    double re[8], im[8];
    if (k < FREQ) {
        double c1, s1;
        if (k == 0)        { c1 =  1.0; s1 =  0.0; }
        else if (k == 50)  { c1 =  0.0; s1 = -1.0; }
        else if (k == 100) { c1 = -1.0; s1 =  0.0; }
        else {
            double ang = -6.283185307179586476925286766559 * (double)k / (double)IN_DIM;
            c1 = cos(ang); s1 = sin(ang);
        }
        double wc = half ? ((k & 1) ? -1.0 : 1.0) : 1.0;   // cis(-pi*k) exact at n=100
        double ws = 0.0;
#pragma unroll
        for (int r = 0; r < 8; ++r) { re[r] = 0.0; im[r] = 0.0; }

        const float* xb = xsT + half * 100 * 8;
        for (int n = 0; n < 100; ++n) {
            const float4* xp = (const float4*)(xb + n * 8);
            float4 x0 = xp[0], x1 = xp[1];
            float xv[8] = {x0.x, x0.y, x0.z, x0.w, x1.x, x1.y, x1.z, x1.w};
#pragma unroll
            for (int r = 0; r < 8; ++r) {
                double xd = (double)xv[r];
                re[r] = fma(xd, wc, re[r]);
                im[r] = fma(xd, ws, im[r]);
            }
            double nwc = wc * c1 - ws * s1;
            double nws = wc * s1 + ws * c1;
            wc = nwc; ws = nws;
        }
        if (half) {
#pragma unroll
            for (int r = 0; r < 8; ++r) { reS[k * 8 + r] = re[r]; imS[k * 8 + r] = im[r]; }
        }
    }
    __syncthreads();
    if (half == 0 && k < FREQ) {
#pragma unroll
        for (int r = 0; r < 8; ++r) { re[r] += reS[k * 8 + r]; im[r] += imS[k * 8 + r]; }
        // overwrite own partial slots with amp/phase (same thread, same addresses)
#pragma unroll
        for (int r = 0; r < 8; ++r) {
            reS[k * 8 + r] = sqrt(re[r] * re[r] + im[r] * im[r]);
            imS[k * 8 + r] = atan2(im[r], re[r]);
        }
    }
    __syncthreads();

    // projection: d = tid&63; which = amp/phase; grp splits the kk range 51/50
    const int d = tid & 63, which = (tid >> 6) & 1, grp = tid >> 7;
    const float*  proj = which ? projP : projA;
    const double* src  = which ? imS : reS;         // [k][r], k-major
    double acc[8];
#pragma unroll
    for (int r = 0; r < 8; ++r) acc[r] = 0.0;
    const int kkA = grp ? 51 : 0;
    const int kkB = grp ? FREQ : 51;
    for (int kk = kkA; kk < kkB; ++kk) {
        double p = (double)proj[kk * VQD + d];
#pragma unroll
        for (int r = 0; r < 8; ++r) acc[r] += src[kk * 8 + r] * p;
    }
    if (grp) {
#pragma unroll
        for (int r = 0; r < 8; ++r) accS[(tid & 127) * 8 + r] = acc[r];
    }
    __syncthreads();
    if (grp == 0) {
#pragma unroll
        for (int r = 0; r < 8; ++r) acc[r] += accS[tid * 8 + r];
#pragma unroll
        for (int r = 0; r < 8; ++r) {
            size_t rowi = (size_t)which * ROWS + r0 + r;
            float vf = (float)acc[r];
            unsigned short hb = f2bf(vf);
            unsigned short lb = f2bf(vf - bf2f(hb));
            ftH[rowi * VQD + d] = hb;
            ftL[rowi * VQD + d] = lb;
            featD[rowi * VQD + d] = acc[r];
        }
    }
}

// ---------------- 2. bf16x3 MFMA sim + top-2, DMA double-buffered prefetch ----------------
// (round-10 version, byte-identical: best measured; argmax is closed at ~150 us — MFMA
// pipe at the bf16x3 algorithmic floor, selection VALU near op-count floor, residual
// idle resisted 4 structural attacks)
#define MFMA(a, b, c) __builtin_amdgcn_mfma_f32_16x16x32_bf16(a, b, c, 0, 0, 0)
#define UPD(val, s) do { float _v = (val); \
    bool _c1 = _v > b1v[s]; bool _c2 = _v > b2v[s]; \
    b2v[s] = _c1 ? b1v[s] : (_c2 ? _v : b2v[s]); \
    b2i[s] = _c1 ? b1i[s] : (_c2 ? idx : b2i[s]); \
    b1v[s] = _c1 ? _v : b1v[s]; \
    b1i[s] = _c1 ? idx : b1i[s]; } while (0)

__global__ __launch_bounds__(256, 3) void argmax_kernel(
    const unsigned short* __restrict__ ftH, const unsigned short* __restrict__ ftL,
    const unsigned short* __restrict__ cbH, const unsigned short* __restrict__ cbL,
    int* __restrict__ pi1, int* __restrict__ pi2)
{
    __shared__ __align__(16) char lds[33792];
    const int tid = threadIdx.x;
    const int f = blockIdx.y, z = blockIdx.z;
    const int r0 = blockIdx.x * 128;
    const int w = tid >> 6, lane = tid & 63;
    const int q = lane >> 4, cl = lane & 15;

    const unsigned short* ftHb = ftH + (size_t)f * ROWS * VQD;
    const unsigned short* ftLb = ftL + (size_t)f * ROWS * VQD;
    const unsigned short* cbHb = cbH + (size_t)f * NEMB * VQD;
    const unsigned short* cbLb = cbL + (size_t)f * NEMB * VQD;

    short8 aH00, aH01, aH10, aH11, aL00, aL01, aL10, aL11;
    {
        const size_t baseA = (size_t)(r0 + w * 32 + cl) * VQD + q * 8;
        const size_t baseB = baseA + (size_t)16 * VQD;
        aH00 = *(const short8*)(ftHb + baseA);
        aH01 = *(const short8*)(ftHb + baseA + 32);
        aH10 = *(const short8*)(ftHb + baseB);
        aH11 = *(const short8*)(ftHb + baseB + 32);
        aL00 = *(const short8*)(ftLb + baseA);
        aL01 = *(const short8*)(ftLb + baseA + 32);
        aL10 = *(const short8*)(ftLb + baseB);
        aL11 = *(const short8*)(ftLb + baseB + 32);
    }

    float b1v[8], b2v[8]; int b1i[8], b2i[8];
#pragma unroll
    for (int s = 0; s < 8; ++s) { b1v[s] = -INFINITY; b2v[s] = -INFINITY; b1i[s] = 0; b2i[s] = 0; }

    const int cBase = tid >> 3;
    const int jel   = (((tid & 7) ^ (cBase & 7)) << 3);
    const unsigned short* gH = cbHb + (size_t)(z * 2048 + cBase) * VQD + jel;
    const unsigned short* gL = cbLb + (size_t)(z * 2048 + cBase) * VQD + jel;

    const int p0 = ((q ^ (cl & 7)) << 4);
    const int p1 = p0 ^ 64;

#pragma unroll
    for (int r = 0; r < 2; ++r) {
        const size_t gofs = (size_t)(32 * r) * VQD;
        GLOAD_LDS(gH + gofs, lds + w * 1024 + r * 4096);
        GLOAD_LDS(gL + gofs, lds + 8192 + w * 1024 + r * 4096);
    }

    for (int it = 0; it < 32; ++it) {
        __syncthreads();
        if (it < 31) {
            char* nbuf = lds + ((it + 1) & 1) * 16384;
            const size_t gbase = (size_t)((it + 1) * 64) * VQD;
#pragma unroll
            for (int r = 0; r < 2; ++r) {
                const size_t gofs = gbase + (size_t)(32 * r) * VQD;
                GLOAD_LDS(gH + gofs, nbuf + w * 1024 + r * 4096);
                GLOAD_LDS(gL + gofs, nbuf + 8192 + w * 1024 + r * 4096);
            }
        }

        const char* buf = lds + (it & 1) * 16384;
        const int cbase = z * 2048 + it * 64;
#pragma unroll
        for (int nt = 0; nt < 4; ++nt) {
            const char* row = buf + (nt * 16 + cl) * 128;
            short8 bH0 = *(const short8*)(row + p0);
            short8 bH1 = *(const short8*)(row + p1);
            short8 bL0 = *(const short8*)(row + 8192 + p0);
            short8 bL1 = *(const short8*)(row + 8192 + p1);

            floatx4 acc0 = {0.f, 0.f, 0.f, 0.f};
            floatx4 acc1 = {0.f, 0.f, 0.f, 0.f};
            acc0 = MFMA(aH00, bH0, acc0);  acc1 = MFMA(aH10, bH0, acc1);
            acc0 = MFMA(aH01, bH1, acc0);  acc1 = MFMA(aH11, bH1, acc1);
            acc0 = MFMA(aH00, bL0, acc0);  acc1 = MFMA(aH10, bL0, acc1);
            acc0 = MFMA(aH01, bL1, acc0);  acc1 = MFMA(aH11, bL1, acc1);
            acc0 = MFMA(aL00, bH0, acc0);  acc1 = MFMA(aL10, bH0, acc1);
            acc0 = MFMA(aL01, bH1, acc0);  acc1 = MFMA(aL11, bH1, acc1);

            const int idx = cbase + nt * 16 + cl;
#pragma unroll
            for (int i = 0; i < 4; ++i) { UPD(acc0[i], i); UPD(acc1[i], 4 + i); }
        }
    }

    __syncthreads();
    float* redv = (float*)lds;           // [128][33]
    int*   redi = (int*)(lds + 128 * 33 * 4);
#pragma unroll
    for (int s = 0; s < 8; ++s) {
        int rowl = w * 32 + ((s & 4) << 2) + q * 4 + (s & 3);
        int base = rowl * 33 + cl * 2;
        redv[base]     = b1v[s]; redi[base]     = b1i[s];
        redv[base + 1] = b2v[s]; redi[base + 1] = b2i[s];
    }
    __syncthreads();
    if (tid < 128) {
        float v1 = -INFINITY, v2 = -INFINITY; int i1 = 0x7fffffff, i2 = 0x7fffffff;
        for (int e = 0; e < 32; ++e) {
            float v = redv[tid * 33 + e]; int id = redi[tid * 33 + e];
            if (v > v1 || (v == v1 && id < i1)) { v2 = v1; i2 = i1; v1 = v; i1 = id; }
            else if (v > v2 || (v == v2 && id < i2)) { v2 = v; i2 = id; }
        }
        size_t p = ((size_t)(f * 4 + z)) * ROWS + r0 + tid;
        pi1[p] = i1; pi2[p] = i2;
    }
}

// ---------------- 3. f64 rescore of the 8 candidates/row (round-5 version) ----------------
__global__ __launch_bounds__(256) void rescore_kernel(
    const double* __restrict__ featD, const double* __restrict__ invnD,
    const float* __restrict__ cbA, const float* __restrict__ cbP,
    const int* __restrict__ pi1, const int* __restrict__ pi2,
    int* __restrict__ out)
{
    const int tid = threadIdx.x;
    const int lane = tid & 63, wave = tid >> 6;
    const int task = blockIdx.x * 4 + wave;           // 0 .. 2*ROWS-1
    const int f = task / ROWS;
    const int row = task - f * ROWS;
    const float* cb = f ? cbP : cbA;
    const double fd = featD[((size_t)f * ROWS + row) * VQD + lane];

    int idxs[8];
#pragma unroll
    for (int c = 0; c < 8; ++c) {
        int zz = c >> 1;
        size_t p = ((size_t)(f * 4 + zz)) * ROWS + row;
        idxs[c] = (c & 1) ? pi2[p] : pi1[p];
    }
    double cv[8];
#pragma unroll
    for (int c = 0; c < 8; ++c)
        cv[c] = (double)cb[(size_t)idxs[c] * VQD + lane];

    double bestv = -1.0e300; int besti = 0x7fffffff;
#pragma unroll
    for (int c = 0; c < 8; ++c) {
        double t = fd * cv[c];
        for (int m = 32; m >= 1; m >>= 1) t += __shfl_xor(t, m, 64);
        double sim = t * invnD[(size_t)f * NEMB + idxs[c]];
        int idx = idxs[c];
        if (sim > bestv || (sim == bestv && idx < besti)) { bestv = sim; besti = idx; }
    }
    if (lane == 0) out[task] = besti;
}

// ---------------- launch ----------------
extern "C" void kernel_launch(void* const* d_in, const int* in_sizes, int n_in,
                              void* d_out, int out_size, void* d_ws, size_t ws_size,
                              hipStream_t stream)
{
    const float* x     = (const float*)d_in[0];
    const float* projA = (const float*)d_in[1];
    const float* projP = (const float*)d_in[2];
    const float* cbA   = (const float*)d_in[3];
    const float* cbP   = (const float*)d_in[4];

    char* ws = (char*)d_ws;
    unsigned short* ftH   = (unsigned short*)(ws + OFF_FTH);
    unsigned short* ftL   = (unsigned short*)(ws + OFF_FTL);
    unsigned short* cbHp  = (unsigned short*)(ws + OFF_CBH);
    unsigned short* cbLp  = (unsigned short*)(ws + OFF_CBL);
    double*         featD = (double*)(ws + OFF_FD);
    double*         invnD = (double*)(ws + OFF_INV);
    int*            pi1   = (int*)(ws + OFF_PI1);
    int*            pi2   = (int*)(ws + OFF_PI2);

    dft_cb_kernel<<<DFT_BLOCKS + 256, 256, 0, stream>>>(
        x, projA, projP, cbA, cbP, ftH, ftL, featD, cbHp, cbLp, invnD);
    argmax_kernel<<<dim3(ROWS / 128, 2, 4), 256, 0, stream>>>(ftH, ftL, cbHp, cbLp, pi1, pi2);
    rescore_kernel<<<(2 * ROWS) / 4, 256, 0, stream>>>(featD, invnD, cbA, cbP, pi1, pi2, (int*)d_out);
}

// Round 15
// 323.445 us; speedup vs baseline: 1.0698x; 1.0052x over previous
//
#include <hip/hip_runtime.h>
#include <math.h>

// Problem constants
constexpr int ROWS  = 19456;   // B*C*N = 16*19*64
constexpr int IN_DIM = 200;
constexpr int FREQ  = 101;     // rfft bins
constexpr int VQD   = 64;
constexpr int NEMB  = 8192;
constexpr int DFT_BLOCKS = ROWS / 8;   // 2432

typedef __attribute__((ext_vector_type(8))) short short8;   // 8 bf16 = 4 VGPRs
typedef __attribute__((ext_vector_type(4))) float floatx4;

__device__ __forceinline__ unsigned short f2bf(float v) {   // RTN-even fp32->bf16
    unsigned int u = __builtin_bit_cast(unsigned int, v);
    unsigned int r = u + 0x7fffu + ((u >> 16) & 1u);
    return (unsigned short)(r >> 16);
}
__device__ __forceinline__ float bf2f(unsigned short b) {
    unsigned int u = ((unsigned int)b) << 16;
    return __builtin_bit_cast(float, u);
}

// async global->LDS DMA, 16 B per lane; LDS dest = wave-uniform base + lane*16
#define GLOAD_LDS(gp, lp) __builtin_amdgcn_global_load_lds( \
    (const __attribute__((address_space(1))) unsigned int*)(gp), \
    (__attribute__((address_space(3))) unsigned int*)(lp), 16, 0, 0)

// ---------------- workspace layout ----------------
constexpr size_t align256(size_t x) { return (x + 255) & ~(size_t)255; }
constexpr size_t SZ_FB    = (size_t)2 * ROWS * VQD * sizeof(unsigned short); // bf16 feats [2][ROWS][64]
constexpr size_t OFF_FTH  = 0;
constexpr size_t OFF_FTL  = align256(OFF_FTH + SZ_FB);
constexpr size_t SZ_CBB   = (size_t)2 * NEMB * VQD * sizeof(unsigned short); // bf16 codes [2][8192][64]
constexpr size_t OFF_CBH  = align256(OFF_FTL + SZ_FB);
constexpr size_t OFF_CBL  = align256(OFF_CBH + SZ_CBB);
constexpr size_t SZ_FD    = (size_t)2 * ROWS * VQD * sizeof(double);         // f64 feats
constexpr size_t OFF_FD   = align256(OFF_CBL + SZ_CBB);
constexpr size_t SZ_INV   = (size_t)2 * NEMB * sizeof(double);               // f64 1/||cb||
constexpr size_t OFF_INV  = align256(OFF_FD + SZ_FD);
constexpr size_t SZ_PI    = (size_t)2 * 4 * ROWS * sizeof(int);              // top-2 per 2048-chunk
constexpr size_t OFF_PI1  = align256(OFF_INV + SZ_INV);
constexpr size_t OFF_PI2  = align256(OFF_PI1 + SZ_PI);

// ---------------- 1. fused DFT/proj (blocks < 2432) + cb_prep (blocks >= 2432) ----------------
// DFT: 8 rows/block, 256 threads. n-loop split across thread-halves: half 1 starts at
// n=100 with the EXACT twiddle cis(-pi k) = ((-1)^k, +0) -- signed-zero accumulation for
// k=0/100 unchanged (im stays +0, atan2(+0, re<0) = +pi matches numpy). Partial (re,im)
// and projection kk-split partials combine via LDS; the f64 reorder is ~1e-16 relative,
// far inside the ~2e-14 perturbation already validated (table->recurrence switch, r3->r4).
__global__ __launch_bounds__(256) void dft_cb_kernel(
    const float* __restrict__ x, const float* __restrict__ projA, const float* __restrict__ projP,
    const float* __restrict__ cbA, const float* __restrict__ cbP,
    unsigned short* __restrict__ ftH, unsigned short* __restrict__ ftL, double* __restrict__ featD,
    unsigned short* __restrict__ cbH, unsigned short* __restrict__ cbL, double* __restrict__ invnD)
{
    __shared__ __align__(16) char smem[21120];
    const int tid = threadIdx.x;

    if (blockIdx.x >= DFT_BLOCKS) {
        // ---- cb_prep body (validated rounds 5-10) ----
        float* tile = (float*)smem;            // 64*65*4 = 16640 B
        float* inv  = (float*)(smem + 16640);  // 256 B
        const int bid2 = blockIdx.x - DFT_BLOCKS;
        const int which = bid2 >> 7;
        const int m0 = (bid2 & 127) * 64;
        const float* cb = which ? cbP : cbA;
        for (int e = tid; e < 4096; e += 256) {
            int c = e >> 6, d = e & 63;
            tile[c * 65 + d] = cb[(size_t)(m0 + c) * VQD + d];
        }
        __syncthreads();
        if (tid < 64) {
            double s = 0.0;
            for (int d2 = 0; d2 < 64; ++d2) { double v = (double)tile[tid * 65 + d2]; s += v * v; }
            inv[tid] = (float)(1.0 / sqrt(s));
            invnD[(size_t)which * NEMB + m0 + tid] = 1.0 / sqrt(s);
        }
        __syncthreads();
        for (int e = tid; e < 4096; e += 256) {
            int c = e >> 6, d = e & 63;
            float v = tile[c * 65 + d] * inv[c];
            unsigned short hb = f2bf(v);
            unsigned short lb = f2bf(v - bf2f(hb));
            size_t o = ((size_t)which * NEMB + m0 + c) * VQD + d;
            cbH[o] = hb; cbL[o] = lb;
        }
        return;
    }

    // ---- DFT + amp/phase + projection ----
    float*  xsT  = (float*)smem;                    // [n][r] 6400 B (region reused for proj partials)
    double* reS  = (double*)(smem + 8192);          // [k][r] 6464 B: half-1 partials, then amp
    double* imS  = (double*)(smem + 8192 + 6464);   // [k][r] 6464 B: half-1 partials, then phase
    double* accS = (double*)smem;                   // proj partials (8192 B), after xsT is dead
    const int r0 = blockIdx.x * 8;

    for (int e = tid; e < 8 * IN_DIM; e += 256) {
        int r = e / IN_DIM, n = e - r * IN_DIM;
        xsT[n * 8 + r] = x[(size_t)(r0 + r) * IN_DIM + n];
    }
    __syncthreads();

    const int k = tid & 127, half = tid >> 7;
    double re[8], im[8];
    if (k < FREQ) {
        double c1, s1;
        if (k == 0)        { c1 =  1.0; s1 =  0.0; }
        else if (k == 50)  { c1 =  0.0; s1 = -1.0; }
        else if (k == 100) { c1 = -1.0; s1 =  0.0; }
        else {
            double ang = -6.283185307179586476925286766559 * (double)k / (double)IN_DIM;
            c1 = cos(ang); s1 = sin(ang);
        }
        double wc = half ? ((k & 1) ? -1.0 : 1.0) : 1.0;   // cis(-pi*k) exact at n=100
        double ws = 0.0;
#pragma unroll
        for (int r = 0; r < 8; ++r) { re[r] = 0.0; im[r] = 0.0; }

        const float* xb = xsT + half * 100 * 8;
        for (int n = 0; n < 100; ++n) {
            const float4* xp = (const float4*)(xb + n * 8);
            float4 x0 = xp[0], x1 = xp[1];
            float xv[8] = {x0.x, x0.y, x0.z, x0.w, x1.x, x1.y, x1.z, x1.w};
#pragma unroll
            for (int r = 0; r < 8; ++r) {
                double xd = (double)xv[r];
                re[r] = fma(xd, wc, re[r]);
                im[r] = fma(xd, ws, im[r]);
            }
            double nwc = wc * c1 - ws * s1;
            double nws = wc * s1 + ws * c1;
            wc = nwc; ws = nws;
        }
        if (half) {
#pragma unroll
            for (int r = 0; r < 8; ++r) { reS[k * 8 + r] = re[r]; imS[k * 8 + r] = im[r]; }
        }
    }
    __syncthreads();
    if (half == 0 && k < FREQ) {
#pragma unroll
        for (int r = 0; r < 8; ++r) { re[r] += reS[k * 8 + r]; im[r] += imS[k * 8 + r]; }
        // overwrite own partial slots with amp/phase (same thread, same addresses)
#pragma unroll
        for (int r = 0; r < 8; ++r) {
            reS[k * 8 + r] = sqrt(re[r] * re[r] + im[r] * im[r]);
            imS[k * 8 + r] = atan2(im[r], re[r]);
        }
    }
    __syncthreads();

    // projection: d = tid&63; which = amp/phase; grp splits the kk range 51/50
    const int d = tid & 63, which = (tid >> 6) & 1, grp = tid >> 7;
    const float*  proj = which ? projP : projA;
    const double* src  = which ? imS : reS;         // [k][r], k-major
    double acc[8];
#pragma unroll
    for (int r = 0; r < 8; ++r) acc[r] = 0.0;
    const int kkA = grp ? 51 : 0;
    const int kkB = grp ? FREQ : 51;
    for (int kk = kkA; kk < kkB; ++kk) {
        double p = (double)proj[kk * VQD + d];
#pragma unroll
        for (int r = 0; r < 8; ++r) acc[r] += src[kk * 8 + r] * p;
    }
    if (grp) {
#pragma unroll
        for (int r = 0; r < 8; ++r) accS[(tid & 127) * 8 + r] = acc[r];
    }
    __syncthreads();
    if (grp == 0) {
#pragma unroll
        for (int r = 0; r < 8; ++r) acc[r] += accS[tid * 8 + r];
#pragma unroll
        for (int r = 0; r < 8; ++r) {
            size_t rowi = (size_t)which * ROWS + r0 + r;
            float vf = (float)acc[r];
            unsigned short hb = f2bf(vf);
            unsigned short lb = f2bf(vf - bf2f(hb));
            ftH[rowi * VQD + d] = hb;
            ftL[rowi * VQD + d] = lb;
            featD[rowi * VQD + d] = acc[r];
        }
    }
}

// ---------------- 2. bf16x3 MFMA sim + top-2, DMA double-buffered prefetch ----------------
// (round-10 version, byte-identical: best measured; argmax is closed at ~153 us — MFMA
// pipe at the bf16x3 algorithmic floor, selection VALU near op-count floor, residual
// idle resisted 4 structural attacks)
#define MFMA(a, b, c) __builtin_amdgcn_mfma_f32_16x16x32_bf16(a, b, c, 0, 0, 0)
#define UPD(val, s) do { float _v = (val); \
    bool _c1 = _v > b1v[s]; bool _c2 = _v > b2v[s]; \
    b2v[s] = _c1 ? b1v[s] : (_c2 ? _v : b2v[s]); \
    b2i[s] = _c1 ? b1i[s] : (_c2 ? idx : b2i[s]); \
    b1v[s] = _c1 ? _v : b1v[s]; \
    b1i[s] = _c1 ? idx : b1i[s]; } while (0)

__global__ __launch_bounds__(256, 3) void argmax_kernel(
    const unsigned short* __restrict__ ftH, const unsigned short* __restrict__ ftL,
    const unsigned short* __restrict__ cbH, const unsigned short* __restrict__ cbL,
    int* __restrict__ pi1, int* __restrict__ pi2)
{
    __shared__ __align__(16) char lds[33792];
    const int tid = threadIdx.x;
    const int f = blockIdx.y, z = blockIdx.z;
    const int r0 = blockIdx.x * 128;
    const int w = tid >> 6, lane = tid & 63;
    const int q = lane >> 4, cl = lane & 15;

    const unsigned short* ftHb = ftH + (size_t)f * ROWS * VQD;
    const unsigned short* ftLb = ftL + (size_t)f * ROWS * VQD;
    const unsigned short* cbHb = cbH + (size_t)f * NEMB * VQD;
    const unsigned short* cbLb = cbL + (size_t)f * NEMB * VQD;

    short8 aH00, aH01, aH10, aH11, aL00, aL01, aL10, aL11;
    {
        const size_t baseA = (size_t)(r0 + w * 32 + cl) * VQD + q * 8;
        const size_t baseB = baseA + (size_t)16 * VQD;
        aH00 = *(const short8*)(ftHb + baseA);
        aH01 = *(const short8*)(ftHb + baseA + 32);
        aH10 = *(const short8*)(ftHb + baseB);
        aH11 = *(const short8*)(ftHb + baseB + 32);
        aL00 = *(const short8*)(ftLb + baseA);
        aL01 = *(const short8*)(ftLb + baseA + 32);
        aL10 = *(const short8*)(ftLb + baseB);
        aL11 = *(const short8*)(ftLb + baseB + 32);
    }

    float b1v[8], b2v[8]; int b1i[8], b2i[8];
#pragma unroll
    for (int s = 0; s < 8; ++s) { b1v[s] = -INFINITY; b2v[s] = -INFINITY; b1i[s] = 0; b2i[s] = 0; }

    const int cBase = tid >> 3;
    const int jel   = (((tid & 7) ^ (cBase & 7)) << 3);
    const unsigned short* gH = cbHb + (size_t)(z * 2048 + cBase) * VQD + jel;
    const unsigned short* gL = cbLb + (size_t)(z * 2048 + cBase) * VQD + jel;

    const int p0 = ((q ^ (cl & 7)) << 4);
    const int p1 = p0 ^ 64;

#pragma unroll
    for (int r = 0; r < 2; ++r) {
        const size_t gofs = (size_t)(32 * r) * VQD;
        GLOAD_LDS(gH + gofs, lds + w * 1024 + r * 4096);
        GLOAD_LDS(gL + gofs, lds + 8192 + w * 1024 + r * 4096);
    }

    for (int it = 0; it < 32; ++it) {
        __syncthreads();
        if (it < 31) {
            char* nbuf = lds + ((it + 1) & 1) * 16384;
            const size_t gbase = (size_t)((it + 1) * 64) * VQD;
#pragma unroll
            for (int r = 0; r < 2; ++r) {
                const size_t gofs = gbase + (size_t)(32 * r) * VQD;
                GLOAD_LDS(gH + gofs, nbuf + w * 1024 + r * 4096);
                GLOAD_LDS(gL + gofs, nbuf + 8192 + w * 1024 + r * 4096);
            }
        }

        const char* buf = lds + (it & 1) * 16384;
        const int cbase = z * 2048 + it * 64;
#pragma unroll
        for (int nt = 0; nt < 4; ++nt) {
            const char* row = buf + (nt * 16 + cl) * 128;
            short8 bH0 = *(const short8*)(row + p0);
            short8 bH1 = *(const short8*)(row + p1);
            short8 bL0 = *(const short8*)(row + 8192 + p0);
            short8 bL1 = *(const short8*)(row + 8192 + p1);

            floatx4 acc0 = {0.f, 0.f, 0.f, 0.f};
            floatx4 acc1 = {0.f, 0.f, 0.f, 0.f};
            acc0 = MFMA(aH00, bH0, acc0);  acc1 = MFMA(aH10, bH0, acc1);
            acc0 = MFMA(aH01, bH1, acc0);  acc1 = MFMA(aH11, bH1, acc1);
            acc0 = MFMA(aH00, bL0, acc0);  acc1 = MFMA(aH10, bL0, acc1);
            acc0 = MFMA(aH01, bL1, acc0);  acc1 = MFMA(aH11, bL1, acc1);
            acc0 = MFMA(aL00, bH0, acc0);  acc1 = MFMA(aL10, bH0, acc1);
            acc0 = MFMA(aL01, bH1, acc0);  acc1 = MFMA(aL11, bH1, acc1);

            const int idx = cbase + nt * 16 + cl;
#pragma unroll
            for (int i = 0; i < 4; ++i) { UPD(acc0[i], i); UPD(acc1[i], 4 + i); }
        }
    }

    __syncthreads();
    float* redv = (float*)lds;           // [128][33]
    int*   redi = (int*)(lds + 128 * 33 * 4);
#pragma unroll
    for (int s = 0; s < 8; ++s) {
        int rowl = w * 32 + ((s & 4) << 2) + q * 4 + (s & 3);   // +16 when s>=4
        int base = rowl * 33 + cl * 2;
        redv[base]     = b1v[s]; redi[base]     = b1i[s];
        redv[base + 1] = b2v[s]; redi[base + 1] = b2i[s];
    }
    __syncthreads();
    if (tid < 128) {
        float v1 = -INFINITY, v2 = -INFINITY; int i1 = 0x7fffffff, i2 = 0x7fffffff;
        for (int e = 0; e < 32; ++e) {
            float v = redv[tid * 33 + e]; int id = redi[tid * 33 + e];
            if (v > v1 || (v == v1 && id < i1)) { v2 = v1; i2 = i1; v1 = v; i1 = id; }
            else if (v > v2 || (v == v2 && id < i2)) { v2 = v; i2 = id; }
        }
        size_t p = ((size_t)(f * 4 + z)) * ROWS + r0 + tid;
        pi1[p] = i1; pi2[p] = i2;
    }
}

// ---------------- 3. f64 rescore of the 8 candidates/row (round-5 version) ----------------
__global__ __launch_bounds__(256) void rescore_kernel(
    const double* __restrict__ featD, const double* __restrict__ invnD,
    const float* __restrict__ cbA, const float* __restrict__ cbP,
    const int* __restrict__ pi1, const int* __restrict__ pi2,
    int* __restrict__ out)
{
    const int tid = threadIdx.x;
    const int lane = tid & 63, wave = tid >> 6;
    const int task = blockIdx.x * 4 + wave;           // 0 .. 2*ROWS-1
    const int f = task / ROWS;
    const int row = task - f * ROWS;
    const float* cb = f ? cbP : cbA;
    const double fd = featD[((size_t)f * ROWS + row) * VQD + lane];

    int idxs[8];
#pragma unroll
    for (int c = 0; c < 8; ++c) {
        int zz = c >> 1;
        size_t p = ((size_t)(f * 4 + zz)) * ROWS + row;
        idxs[c] = (c & 1) ? pi2[p] : pi1[p];
    }
    double cv[8];
#pragma unroll
    for (int c = 0; c < 8; ++c)
        cv[c] = (double)cb[(size_t)idxs[c] * VQD + lane];

    double bestv = -1.0e300; int besti = 0x7fffffff;
#pragma unroll
    for (int c = 0; c < 8; ++c) {
        double t = fd * cv[c];
        for (int m = 32; m >= 1; m >>= 1) t += __shfl_xor(t, m, 64);
        double sim = t * invnD[(size_t)f * NEMB + idxs[c]];
        int idx = idxs[c];
        if (sim > bestv || (sim == bestv && idx < besti)) { bestv = sim; besti = idx; }
    }
    if (lane == 0) out[task] = besti;
}

// ---------------- launch ----------------
extern "C" void kernel_launch(void* const* d_in, const int* in_sizes, int n_in,
                              void* d_out, int out_size, void* d_ws, size_t ws_size,
                              hipStream_t stream)
{
    const float* x     = (const float*)d_in[0];
    const float* projA = (const float*)d_in[1];
    const float* projP = (const float*)d_in[2];
    const float* cbA   = (const float*)d_in[3];
    const float* cbP   = (const float*)d_in[4];

    char* ws = (char*)d_ws;
    unsigned short* ftH   = (unsigned short*)(ws + OFF_FTH);
    unsigned short* ftL   = (unsigned short*)(ws + OFF_FTL);
    unsigned short* cbHp  = (unsigned short*)(ws + OFF_CBH);
    unsigned short* cbLp  = (unsigned short*)(ws + OFF_CBL);
    double*         featD = (double*)(ws + OFF_FD);
    double*         invnD = (double*)(ws + OFF_INV);
    int*            pi1   = (int*)(ws + OFF_PI1);
    int*            pi2   = (int*)(ws + OFF_PI2);

    dft_cb_kernel<<<DFT_BLOCKS + 256, 256, 0, stream>>>(
        x, projA, projP, cbA, cbP, ftH, ftL, featD, cbHp, cbLp, invnD);
    argmax_kernel<<<dim3(ROWS / 128, 2, 4), 256, 0, stream>>>(ftH, ftL, cbHp, cbLp, pi1, pi2);
    rescore_kernel<<<(2 * ROWS) / 4, 256, 0, stream>>>(featD, invnD, cbA, cbP, pi1, pi2, (int*)d_out);
}

// Round 16
// 315.230 us; speedup vs baseline: 1.0977x; 1.0261x over previous
//
#include <hip/hip_runtime.h>
#include <math.h>

// Problem constants
constexpr int ROWS  = 19456;   // B*C*N = 16*19*64
constexpr int IN_DIM = 200;
constexpr int FREQ  = 101;     // rfft bins
constexpr int VQD   = 64;
constexpr int NEMB  = 8192;
constexpr int DFT_BLOCKS = ROWS / 8;   // 2432

typedef __attribute__((ext_vector_type(8))) short short8;   // 8 bf16 = 4 VGPRs
typedef __attribute__((ext_vector_type(4))) float floatx4;

__device__ __forceinline__ unsigned short f2bf(float v) {   // RTN-even fp32->bf16
    unsigned int u = __builtin_bit_cast(unsigned int, v);
    unsigned int r = u + 0x7fffu + ((u >> 16) & 1u);
    return (unsigned short)(r >> 16);
}
__device__ __forceinline__ float bf2f(unsigned short b) {
    unsigned int u = ((unsigned int)b) << 16;
    return __builtin_bit_cast(float, u);
}

// cis(-2*pi*r/200) with exact quarter points (bitwise-identical to the r1-validated table)
__device__ __forceinline__ void cis_exact(int r, double& c, double& s) {
    if (r == 0)        { c =  1.0; s =  0.0; }
    else if (r == 50)  { c =  0.0; s = -1.0; }
    else if (r == 100) { c = -1.0; s =  0.0; }
    else if (r == 150) { c =  0.0; s =  1.0; }
    else {
        double ang = -6.283185307179586476925286766559 * (double)r / (double)IN_DIM;
        c = cos(ang); s = sin(ang);
    }
}

// async global->LDS DMA, 16 B per lane; LDS dest = wave-uniform base + lane*16
#define GLOAD_LDS(gp, lp) __builtin_amdgcn_global_load_lds( \
    (const __attribute__((address_space(1))) unsigned int*)(gp), \
    (__attribute__((address_space(3))) unsigned int*)(lp), 16, 0, 0)

// ---------------- workspace layout ----------------
constexpr size_t align256(size_t x) { return (x + 255) & ~(size_t)255; }
constexpr size_t SZ_FB    = (size_t)2 * ROWS * VQD * sizeof(unsigned short); // bf16 feats [2][ROWS][64]
constexpr size_t OFF_FTH  = 0;
constexpr size_t OFF_FTL  = align256(OFF_FTH + SZ_FB);
constexpr size_t SZ_CBB   = (size_t)2 * NEMB * VQD * sizeof(unsigned short); // bf16 codes [2][8192][64]
constexpr size_t OFF_CBH  = align256(OFF_FTL + SZ_FB);
constexpr size_t OFF_CBL  = align256(OFF_CBH + SZ_CBB);
constexpr size_t SZ_FD    = (size_t)2 * ROWS * VQD * sizeof(double);         // f64 feats
constexpr size_t OFF_FD   = align256(OFF_CBL + SZ_CBB);
constexpr size_t SZ_INV   = (size_t)2 * NEMB * sizeof(double);               // f64 1/||cb||
constexpr size_t OFF_INV  = align256(OFF_FD + SZ_FD);
constexpr size_t SZ_PI    = (size_t)2 * 4 * ROWS * sizeof(int);              // top-2 per 2048-chunk
constexpr size_t OFF_PI1  = align256(OFF_INV + SZ_INV);
constexpr size_t OFF_PI2  = align256(OFF_PI1 + SZ_PI);

// ---------------- 1. fused DFT/proj (blocks < 2432) + cb_prep (blocks >= 2432) ----------------
// DFT with conjugate-symmetry pairing: cis(-2pi(200-n)k/200) = conj(cis(-2pi n k/200)), so
//   re += (x[n]+x[200-n])*wc ; im += (x[n]-x[200-n])*ws   -- 2 FMA per 2 samples per row.
// Pair sums (exact in f64) precomputed once into LDS; n-loop iterations halve (100 -> ~50).
// Halves split the pair range: half0 n=1..50, half1 n=51..99 + singles n=0,100.
// Exactness: half-1 start twiddle via integer reduction r=(51k)%200 with exact quarter
// points (k=100 -> r=100 -> (-1,+0); k=50 -> r=150 -> (0,+1)); s1=+0 keeps ws in {+-0}
// and im accumulates exactly +0 for k in {0,100} (RN: +0 + -0 = +0) -> atan2(+0,re<0)=+pi
// matches numpy (r4-validated argument, unchanged). Other reorderings are the ~1e-16
// class validated at r10->r11.
__global__ __launch_bounds__(256) void dft_cb_kernel(
    const float* __restrict__ x, const float* __restrict__ projA, const float* __restrict__ projP,
    const float* __restrict__ cbA, const float* __restrict__ cbP,
    unsigned short* __restrict__ ftH, unsigned short* __restrict__ ftL, double* __restrict__ featD,
    unsigned short* __restrict__ cbH, unsigned short* __restrict__ cbL, double* __restrict__ invnD)
{
    // region plan (8-aligned):
    //   [    0,  6400) xsT  f32 [n=200][r=8]      (later: accS f64 proj partials [0,8192))
    //   [ 6400, 12800) xp   f64 [n=0..99][8]      (n used 1..99; first 1792 B also recycled by accS)
    //   [12800, 19200) xm   f64
    //   [19200, 25664) reS  f64 [k][8]  half-1 partials, then amp
    //   [25664, 32128) imS  f64 [k][8]  half-1 partials, then phase
    __shared__ __align__(16) char smem[32128];
    const int tid = threadIdx.x;

    if (blockIdx.x >= DFT_BLOCKS) {
        // ---- cb_prep body (validated rounds 5-15) ----
        float* tile = (float*)smem;            // 64*65*4 = 16640 B
        float* inv  = (float*)(smem + 16640);  // 256 B
        const int bid2 = blockIdx.x - DFT_BLOCKS;
        const int which = bid2 >> 7;
        const int m0 = (bid2 & 127) * 64;
        const float* cb = which ? cbP : cbA;
        for (int e = tid; e < 4096; e += 256) {
            int c = e >> 6, d = e & 63;
            tile[c * 65 + d] = cb[(size_t)(m0 + c) * VQD + d];
        }
        __syncthreads();
        if (tid < 64) {
            double s = 0.0;
            for (int d2 = 0; d2 < 64; ++d2) { double v = (double)tile[tid * 65 + d2]; s += v * v; }
            inv[tid] = (float)(1.0 / sqrt(s));
            invnD[(size_t)which * NEMB + m0 + tid] = 1.0 / sqrt(s);
        }
        __syncthreads();
        for (int e = tid; e < 4096; e += 256) {
            int c = e >> 6, d = e & 63;
            float v = tile[c * 65 + d] * inv[c];
            unsigned short hb = f2bf(v);
            unsigned short lb = f2bf(v - bf2f(hb));
            size_t o = ((size_t)which * NEMB + m0 + c) * VQD + d;
            cbH[o] = hb; cbL[o] = lb;
        }
        return;
    }

    float*  xsT  = (float*)smem;                    // [n][r]
    double* xpD  = (double*)(smem + 6400);          // [n][r], n=1..99
    double* xmD  = (double*)(smem + 12800);
    double* reS  = (double*)(smem + 19200);         // [k][r]: half-1 partials, then amp
    double* imS  = (double*)(smem + 25664);         //          half-1 partials, then phase
    double* accS = (double*)smem;                   // proj partials (8192 B), after xsT/xp dead
    const int r0 = blockIdx.x * 8;

    for (int e = tid; e < 8 * IN_DIM; e += 256) {
        int r = e / IN_DIM, n = e - r * IN_DIM;
        xsT[n * 8 + r] = x[(size_t)(r0 + r) * IN_DIM + n];
    }
    __syncthreads();

    // pair build: xp[n][r] = x[n]+x[200-n], xm[n][r] = x[n]-x[200-n]  (exact in f64)
    for (int e = tid; e < 99 * 8; e += 256) {
        int n = (e >> 3) + 1, r = e & 7;
        double a = (double)xsT[n * 8 + r];
        double b = (double)xsT[(IN_DIM - n) * 8 + r];
        xpD[n * 8 + r] = a + b;
        xmD[n * 8 + r] = a - b;
    }
    __syncthreads();

    const int k = tid & 127, half = tid >> 7;
    double re[8], im[8];
    if (k < FREQ) {
        double c1, s1;
        cis_exact(k, c1, s1);                        // step multiplier
        const int n0 = half ? 51 : 1;
        double wc, ws;
        cis_exact((int)(((long long)k * n0) % IN_DIM), wc, ws);   // start twiddle, exact quarter pts
#pragma unroll
        for (int r = 0; r < 8; ++r) { re[r] = 0.0; im[r] = 0.0; }
        if (half) {
            // singles n=0 (w=1) and n=100 (w=((-1)^k, +0)); im contribution exactly +-0 -> skip
            double sg = (k & 1) ? -1.0 : 1.0;
#pragma unroll
            for (int r = 0; r < 8; ++r)
                re[r] = (double)xsT[r] + sg * (double)xsT[100 * 8 + r];
        }
        const int nEnd = half ? 100 : 51;            // half0: 1..50, half1: 51..99
        for (int n = n0; n < nEnd; ++n) {
            const double* xpn = xpD + n * 8;
            const double* xmn = xmD + n * 8;
#pragma unroll
            for (int r = 0; r < 8; ++r) {
                re[r] = fma(xpn[r], wc, re[r]);
                im[r] = fma(xmn[r], ws, im[r]);
            }
            double nwc = wc * c1 - ws * s1;
            double nws = wc * s1 + ws * c1;
            wc = nwc; ws = nws;
        }
        if (half) {
#pragma unroll
            for (int r = 0; r < 8; ++r) { reS[k * 8 + r] = re[r]; imS[k * 8 + r] = im[r]; }
        }
    }
    __syncthreads();
    if (half == 0 && k < FREQ) {
#pragma unroll
        for (int r = 0; r < 8; ++r) { re[r] += reS[k * 8 + r]; im[r] += imS[k * 8 + r]; }
        // overwrite own partial slots with amp/phase (same thread, same addresses)
#pragma unroll
        for (int r = 0; r < 8; ++r) {
            reS[k * 8 + r] = sqrt(re[r] * re[r] + im[r] * im[r]);
            imS[k * 8 + r] = atan2(im[r], re[r]);
        }
    }
    __syncthreads();

    // projection: d = tid&63; which = amp/phase; grp splits the kk range 51/50 (r11-validated)
    const int d = tid & 63, which = (tid >> 6) & 1, grp = tid >> 7;
    const float*  proj = which ? projP : projA;
    const double* src  = which ? imS : reS;         // [k][r], k-major
    double acc[8];
#pragma unroll
    for (int r = 0; r < 8; ++r) acc[r] = 0.0;
    const int kkA = grp ? 51 : 0;
    const int kkB = grp ? FREQ : 51;
    for (int kk = kkA; kk < kkB; ++kk) {
        double p = (double)proj[kk * VQD + d];
#pragma unroll
        for (int r = 0; r < 8; ++r) acc[r] += src[kk * 8 + r] * p;
    }
    if (grp) {
#pragma unroll
        for (int r = 0; r < 8; ++r) accS[(tid & 127) * 8 + r] = acc[r];
    }
    __syncthreads();
    if (grp == 0) {
#pragma unroll
        for (int r = 0; r < 8; ++r) acc[r] += accS[tid * 8 + r];
#pragma unroll
        for (int r = 0; r < 8; ++r) {
            size_t rowi = (size_t)which * ROWS + r0 + r;
            float vf = (float)acc[r];
            unsigned short hb = f2bf(vf);
            unsigned short lb = f2bf(vf - bf2f(hb));
            ftH[rowi * VQD + d] = hb;
            ftL[rowi * VQD + d] = lb;
            featD[rowi * VQD + d] = acc[r];
        }
    }
}

// ---------------- 2. bf16x3 MFMA sim + top-2, DMA double-buffered prefetch ----------------
// (round-10 version, byte-identical: best measured; argmax is closed at ~154 us — MFMA
// pipe at the bf16x3 algorithmic floor, selection VALU near op-count floor, residual
// idle resisted 4 structural attacks)
#define MFMA(a, b, c) __builtin_amdgcn_mfma_f32_16x16x32_bf16(a, b, c, 0, 0, 0)
#define UPD(val, s) do { float _v = (val); \
    bool _c1 = _v > b1v[s]; bool _c2 = _v > b2v[s]; \
    b2v[s] = _c1 ? b1v[s] : (_c2 ? _v : b2v[s]); \
    b2i[s] = _c1 ? b1i[s] : (_c2 ? idx : b2i[s]); \
    b1v[s] = _c1 ? _v : b1v[s]; \
    b1i[s] = _c1 ? idx : b1i[s]; } while (0)

__global__ __launch_bounds__(256, 3) void argmax_kernel(
    const unsigned short* __restrict__ ftH, const unsigned short* __restrict__ ftL,
    const unsigned short* __restrict__ cbH, const unsigned short* __restrict__ cbL,
    int* __restrict__ pi1, int* __restrict__ pi2)
{
    __shared__ __align__(16) char lds[33792];
    const int tid = threadIdx.x;
    const int f = blockIdx.y, z = blockIdx.z;
    const int r0 = blockIdx.x * 128;
    const int w = tid >> 6, lane = tid & 63;
    const int q = lane >> 4, cl = lane & 15;

    const unsigned short* ftHb = ftH + (size_t)f * ROWS * VQD;
    const unsigned short* ftLb = ftL + (size_t)f * ROWS * VQD;
    const unsigned short* cbHb = cbH + (size_t)f * NEMB * VQD;
    const unsigned short* cbLb = cbL + (size_t)f * NEMB * VQD;

    short8 aH00, aH01, aH10, aH11, aL00, aL01, aL10, aL11;
    {
        const size_t baseA = (size_t)(r0 + w * 32 + cl) * VQD + q * 8;
        const size_t baseB = baseA + (size_t)16 * VQD;
        aH00 = *(const short8*)(ftHb + baseA);
        aH01 = *(const short8*)(ftHb + baseA + 32);
        aH10 = *(const short8*)(ftHb + baseB);
        aH11 = *(const short8*)(ftHb + baseB + 32);
        aL00 = *(const short8*)(ftLb + baseA);
        aL01 = *(const short8*)(ftLb + baseA + 32);
        aL10 = *(const short8*)(ftLb + baseB);
        aL11 = *(const short8*)(ftLb + baseB + 32);
    }

    float b1v[8], b2v[8]; int b1i[8], b2i[8];
#pragma unroll
    for (int s = 0; s < 8; ++s) { b1v[s] = -INFINITY; b2v[s] = -INFINITY; b1i[s] = 0; b2i[s] = 0; }

    const int cBase = tid >> 3;
    const int jel   = (((tid & 7) ^ (cBase & 7)) << 3);
    const unsigned short* gH = cbHb + (size_t)(z * 2048 + cBase) * VQD + jel;
    const unsigned short* gL = cbLb + (size_t)(z * 2048 + cBase) * VQD + jel;

    const int p0 = ((q ^ (cl & 7)) << 4);
    const int p1 = p0 ^ 64;

#pragma unroll
    for (int r = 0; r < 2; ++r) {
        const size_t gofs = (size_t)(32 * r) * VQD;
        GLOAD_LDS(gH + gofs, lds + w * 1024 + r * 4096);
        GLOAD_LDS(gL + gofs, lds + 8192 + w * 1024 + r * 4096);
    }

    for (int it = 0; it < 32; ++it) {
        __syncthreads();
        if (it < 31) {
            char* nbuf = lds + ((it + 1) & 1) * 16384;
            const size_t gbase = (size_t)((it + 1) * 64) * VQD;
#pragma unroll
            for (int r = 0; r < 2; ++r) {
                const size_t gofs = gbase + (size_t)(32 * r) * VQD;
                GLOAD_LDS(gH + gofs, nbuf + w * 1024 + r * 4096);
                GLOAD_LDS(gL + gofs, nbuf + 8192 + w * 1024 + r * 4096);
            }
        }

        const char* buf = lds + (it & 1) * 16384;
        const int cbase = z * 2048 + it * 64;
#pragma unroll
        for (int nt = 0; nt < 4; ++nt) {
            const char* row = buf + (nt * 16 + cl) * 128;
            short8 bH0 = *(const short8*)(row + p0);
            short8 bH1 = *(const short8*)(row + p1);
            short8 bL0 = *(const short8*)(row + 8192 + p0);
            short8 bL1 = *(const short8*)(row + 8192 + p1);

            floatx4 acc0 = {0.f, 0.f, 0.f, 0.f};
            floatx4 acc1 = {0.f, 0.f, 0.f, 0.f};
            acc0 = MFMA(aH00, bH0, acc0);  acc1 = MFMA(aH10, bH0, acc1);
            acc0 = MFMA(aH01, bH1, acc0);  acc1 = MFMA(aH11, bH1, acc1);
            acc0 = MFMA(aH00, bL0, acc0);  acc1 = MFMA(aH10, bL0, acc1);
            acc0 = MFMA(aH01, bL1, acc0);  acc1 = MFMA(aH11, bL1, acc1);
            acc0 = MFMA(aL00, bH0, acc0);  acc1 = MFMA(aL10, bH0, acc1);
            acc0 = MFMA(aL01, bH1, acc0);  acc1 = MFMA(aL11, bH1, acc1);

            const int idx = cbase + nt * 16 + cl;
#pragma unroll
            for (int i = 0; i < 4; ++i) { UPD(acc0[i], i); UPD(acc1[i], 4 + i); }
        }
    }

    __syncthreads();
    float* redv = (float*)lds;           // [128][33]
    int*   redi = (int*)(lds + 128 * 33 * 4);
#pragma unroll
    for (int s = 0; s < 8; ++s) {
        int rowl = w * 32 + ((s & 4) << 2) + q * 4 + (s & 3);   // +16 when s>=4
        int base = rowl * 33 + cl * 2;
        redv[base]     = b1v[s]; redi[base]     = b1i[s];
        redv[base + 1] = b2v[s]; redi[base + 1] = b2i[s];
    }
    __syncthreads();
    if (tid < 128) {
        float v1 = -INFINITY, v2 = -INFINITY; int i1 = 0x7fffffff, i2 = 0x7fffffff;
        for (int e = 0; e < 32; ++e) {
            float v = redv[tid * 33 + e]; int id = redi[tid * 33 + e];
            if (v > v1 || (v == v1 && id < i1)) { v2 = v1; i2 = i1; v1 = v; i1 = id; }
            else if (v > v2 || (v == v2 && id < i2)) { v2 = v; i2 = id; }
        }
        size_t p = ((size_t)(f * 4 + z)) * ROWS + r0 + tid;
        pi1[p] = i1; pi2[p] = i2;
    }
}

// ---------------- 3. f64 rescore of the 8 candidates/row (round-5 version) ----------------
__global__ __launch_bounds__(256) void rescore_kernel(
    const double* __restrict__ featD, const double* __restrict__ invnD,
    const float* __restrict__ cbA, const float* __restrict__ cbP,
    const int* __restrict__ pi1, const int* __restrict__ pi2,
    int* __restrict__ out)
{
    const int tid = threadIdx.x;
    const int lane = tid & 63, wave = tid >> 6;
    const int task = blockIdx.x * 4 + wave;           // 0 .. 2*ROWS-1
    const int f = task / ROWS;
    const int row = task - f * ROWS;
    const float* cb = f ? cbP : cbA;
    const double fd = featD[((size_t)f * ROWS + row) * VQD + lane];

    int idxs[8];
#pragma unroll
    for (int c = 0; c < 8; ++c) {
        int zz = c >> 1;
        size_t p = ((size_t)(f * 4 + zz)) * ROWS + row;
        idxs[c] = (c & 1) ? pi2[p] : pi1[p];
    }
    double cv[8];
#pragma unroll
    for (int c = 0; c < 8; ++c)
        cv[c] = (double)cb[(size_t)idxs[c] * VQD + lane];

    double bestv = -1.0e300; int besti = 0x7fffffff;
#pragma unroll
    for (int c = 0; c < 8; ++c) {
        double t = fd * cv[c];
        for (int m = 32; m >= 1; m >>= 1) t += __shfl_xor(t, m, 64);
        double sim = t * invnD[(size_t)f * NEMB + idxs[c]];
        int idx = idxs[c];
        if (sim > bestv || (sim == bestv && idx < besti)) { bestv = sim; besti = idx; }
    }
    if (lane == 0) out[task] = besti;
}

// ---------------- launch ----------------
extern "C" void kernel_launch(void* const* d_in, const int* in_sizes, int n_in,
                              void* d_out, int out_size, void* d_ws, size_t ws_size,
                              hipStream_t stream)
{
    const float* x     = (const float*)d_in[0];
    const float* projA = (const float*)d_in[1];
    const float* projP = (const float*)d_in[2];
    const float* cbA   = (const float*)d_in[3];
    const float* cbP   = (const float*)d_in[4];

    char* ws = (char*)d_ws;
    unsigned short* ftH   = (unsigned short*)(ws + OFF_FTH);
    unsigned short* ftL   = (unsigned short*)(ws + OFF_FTL);
    unsigned short* cbHp  = (unsigned short*)(ws + OFF_CBH);
    unsigned short* cbLp  = (unsigned short*)(ws + OFF_CBL);
    double*         featD = (double*)(ws + OFF_FD);
    double*         invnD = (double*)(ws + OFF_INV);
    int*            pi1   = (int*)(ws + OFF_PI1);
    int*            pi2   = (int*)(ws + OFF_PI2);

    dft_cb_kernel<<<DFT_BLOCKS + 256, 256, 0, stream>>>(
        x, projA, projP, cbA, cbP, ftH, ftL, featD, cbHp, cbLp, invnD);
    argmax_kernel<<<dim3(ROWS / 128, 2, 4), 256, 0, stream>>>(ftH, ftL, cbHp, cbLp, pi1, pi2);
    rescore_kernel<<<(2 * ROWS) / 4, 256, 0, stream>>>(featD, invnD, cbA, cbP, pi1, pi2, (int*)d_out);
}

// Round 18
// 314.251 us; speedup vs baseline: 1.1011x; 1.0031x over previous
//
#include <hip/hip_runtime.h>
#include <math.h>

// Problem constants
constexpr int ROWS  = 19456;   // B*C*N = 16*19*64
constexpr int IN_DIM = 200;
constexpr int FREQ  = 101;     // rfft bins
constexpr int VQD   = 64;
constexpr int NEMB  = 8192;
constexpr int DFT_BLOCKS = ROWS / 8;   // 2432

typedef __attribute__((ext_vector_type(8))) short short8;   // 8 bf16 = 4 VGPRs
typedef __attribute__((ext_vector_type(4))) float floatx4;

__device__ __forceinline__ unsigned short f2bf(float v) {   // RTN-even fp32->bf16
    unsigned int u = __builtin_bit_cast(unsigned int, v);
    unsigned int r = u + 0x7fffu + ((u >> 16) & 1u);
    return (unsigned short)(r >> 16);
}
__device__ __forceinline__ float bf2f(unsigned short b) {
    unsigned int u = ((unsigned int)b) << 16;
    return __builtin_bit_cast(float, u);
}

// cis(-2*pi*r/200) with exact quarter points (bitwise-identical to the r1-validated table)
__device__ __forceinline__ void cis_exact(int r, double& c, double& s) {
    if (r == 0)        { c =  1.0; s =  0.0; }
    else if (r == 50)  { c =  0.0; s = -1.0; }
    else if (r == 100) { c = -1.0; s =  0.0; }
    else if (r == 150) { c =  0.0; s =  1.0; }
    else {
        double ang = -6.283185307179586476925286766559 * (double)r / (double)IN_DIM;
        c = cos(ang); s = sin(ang);
    }
}

// async global->LDS DMA, 16 B per lane; LDS dest = wave-uniform base + lane*16
#define GLOAD_LDS(gp, lp) __builtin_amdgcn_global_load_lds( \
    (const __attribute__((address_space(1))) unsigned int*)(gp), \
    (__attribute__((address_space(3))) unsigned int*)(lp), 16, 0, 0)

// ---------------- workspace layout ----------------
constexpr size_t align256(size_t x) { return (x + 255) & ~(size_t)255; }
constexpr size_t SZ_FB    = (size_t)2 * ROWS * VQD * sizeof(unsigned short); // bf16 feats [2][ROWS][64]
constexpr size_t OFF_FTH  = 0;
constexpr size_t OFF_FTL  = align256(OFF_FTH + SZ_FB);
constexpr size_t SZ_CBB   = (size_t)2 * NEMB * VQD * sizeof(unsigned short); // bf16 codes [2][8192][64]
constexpr size_t OFF_CBH  = align256(OFF_FTL + SZ_FB);
constexpr size_t OFF_CBL  = align256(OFF_CBH + SZ_CBB);
constexpr size_t SZ_FD    = (size_t)2 * ROWS * VQD * sizeof(double);         // f64 feats
constexpr size_t OFF_FD   = align256(OFF_CBL + SZ_CBB);
constexpr size_t SZ_INV   = (size_t)2 * NEMB * sizeof(double);               // f64 1/||cb||
constexpr size_t OFF_INV  = align256(OFF_FD + SZ_FD);
constexpr size_t SZ_PI    = (size_t)2 * 4 * ROWS * sizeof(int);              // top-2 per 2048-chunk
constexpr size_t OFF_PI1  = align256(OFF_INV + SZ_INV);
constexpr size_t OFF_PI2  = align256(OFF_PI1 + SZ_PI);

// ---------------- 1. fused DFT/proj (blocks < 2432) + cb_prep (blocks >= 2432) ----------------
// r16 conjugate-symmetry DFT + load-balanced transcendental epilogue.
// r17 FAILURE ROOT CAUSE: parking buffers reused xpD/xmD which hold only 800 doubles
// (n=1..99) but the transfer needs 808 (k=0..100) -> k=100 overflowed into xmD[0..7]
// and reS[0..7], corrupting the k=0 bin. Fixed: park in reT=[0,6464) imT=[6464,12928),
// wholly inside the region dead after the post-DFT barrier (xsT singles + xp/xm reads
// sealed; accS reuses [0,8192) only after the epilogue barrier).
__global__ __launch_bounds__(256) void dft_cb_kernel(
    const float* __restrict__ x, const float* __restrict__ projA, const float* __restrict__ projP,
    const float* __restrict__ cbA, const float* __restrict__ cbP,
    unsigned short* __restrict__ ftH, unsigned short* __restrict__ ftL, double* __restrict__ featD,
    unsigned short* __restrict__ cbH, unsigned short* __restrict__ cbL, double* __restrict__ invnD)
{
    // region plan (8-aligned):
    //   [    0,  6400) xsT  f32 [n=200][r=8]
    //   [ 6400, 12800) xp   f64 [n=1..99][8]
    //   [12800, 19200) xm   f64
    //   [19200, 25664) reS  f64 [k][8]  half-1 partials, then amp
    //   [25664, 32128) imS  f64 [k][8]  half-1 partials, then phase
    //   transfer phase (after post-DFT barrier): reT=[0,6464) imT=[6464,12928)
    //   projection phase (after epilogue barrier): accS=[0,8192)
    __shared__ __align__(16) char smem[32128];
    const int tid = threadIdx.x;

    if (blockIdx.x >= DFT_BLOCKS) {
        // ---- cb_prep body (validated rounds 5-16) ----
        float* tile = (float*)smem;            // 64*65*4 = 16640 B
        float* inv  = (float*)(smem + 16640);  // 256 B
        const int bid2 = blockIdx.x - DFT_BLOCKS;
        const int which = bid2 >> 7;
        const int m0 = (bid2 & 127) * 64;
        const float* cb = which ? cbP : cbA;
        for (int e = tid; e < 4096; e += 256) {
            int c = e >> 6, d = e & 63;
            tile[c * 65 + d] = cb[(size_t)(m0 + c) * VQD + d];
        }
        __syncthreads();
        if (tid < 64) {
            double s = 0.0;
            for (int d2 = 0; d2 < 64; ++d2) { double v = (double)tile[tid * 65 + d2]; s += v * v; }
            inv[tid] = (float)(1.0 / sqrt(s));
            invnD[(size_t)which * NEMB + m0 + tid] = 1.0 / sqrt(s);
        }
        __syncthreads();
        for (int e = tid; e < 4096; e += 256) {
            int c = e >> 6, d = e & 63;
            float v = tile[c * 65 + d] * inv[c];
            unsigned short hb = f2bf(v);
            unsigned short lb = f2bf(v - bf2f(hb));
            size_t o = ((size_t)which * NEMB + m0 + c) * VQD + d;
            cbH[o] = hb; cbL[o] = lb;
        }
        return;
    }

    float*  xsT  = (float*)smem;                    // [n][r]
    double* xpD  = (double*)(smem + 6400);          // [n][r], n=1..99
    double* xmD  = (double*)(smem + 12800);
    double* reS  = (double*)(smem + 19200);         // [k][r]: half-1 partials, then amp
    double* imS  = (double*)(smem + 25664);         //          half-1 partials, then phase
    double* reT  = (double*)smem;                   // transfer: 808 doubles = [0, 6464)
    double* imT  = (double*)(smem + 6464);          // transfer: 808 doubles = [6464, 12928)
    double* accS = (double*)smem;                   // proj partials [0, 8192), after epilogue
    const int r0 = blockIdx.x * 8;

    for (int e = tid; e < 8 * IN_DIM; e += 256) {
        int r = e / IN_DIM, n = e - r * IN_DIM;
        xsT[n * 8 + r] = x[(size_t)(r0 + r) * IN_DIM + n];
    }
    __syncthreads();

    // pair build: xp[n][r] = x[n]+x[200-n], xm[n][r] = x[n]-x[200-n]  (exact in f64)
    for (int e = tid; e < 99 * 8; e += 256) {
        int n = (e >> 3) + 1, r = e & 7;
        double a = (double)xsT[n * 8 + r];
        double b = (double)xsT[(IN_DIM - n) * 8 + r];
        xpD[n * 8 + r] = a + b;
        xmD[n * 8 + r] = a - b;
    }
    __syncthreads();

    const int k = tid & 127, half = tid >> 7;
    double re[8], im[8];
    if (k < FREQ) {
        double c1, s1;
        cis_exact(k, c1, s1);                        // step multiplier
        const int n0 = half ? 51 : 1;
        double wc, ws;
        cis_exact((int)(((long long)k * n0) % IN_DIM), wc, ws);   // start twiddle, exact quarter pts
#pragma unroll
        for (int r = 0; r < 8; ++r) { re[r] = 0.0; im[r] = 0.0; }
        if (half) {
            // singles n=0 (w=1) and n=100 (w=((-1)^k, +0)); im contribution exactly +-0 -> skip
            double sg = (k & 1) ? -1.0 : 1.0;
#pragma unroll
            for (int r = 0; r < 8; ++r)
                re[r] = (double)xsT[r] + sg * (double)xsT[100 * 8 + r];
        }
        const int nEnd = half ? 100 : 51;            // half0: 1..50, half1: 51..99
        for (int n = n0; n < nEnd; ++n) {
            const double* xpn = xpD + n * 8;
            const double* xmn = xmD + n * 8;
#pragma unroll
            for (int r = 0; r < 8; ++r) {
                re[r] = fma(xpn[r], wc, re[r]);
                im[r] = fma(xmn[r], ws, im[r]);
            }
            double nwc = wc * c1 - ws * s1;
            double nws = wc * s1 + ws * c1;
            wc = nwc; ws = nws;
        }
        if (half) {
#pragma unroll
            for (int r = 0; r < 8; ++r) { reS[k * 8 + r] = re[r]; imS[k * 8 + r] = im[r]; }
        }
    }
    __syncthreads();
    // combine halves; park final (re,im) in reT/imT (dead region, correctly sized 808 doubles)
    if (half == 0 && k < FREQ) {
#pragma unroll
        for (int r = 0; r < 8; ++r) { re[r] += reS[k * 8 + r]; im[r] += imS[k * 8 + r]; }
#pragma unroll
        for (int r = 0; r < 8; ++r) { reT[k * 8 + r] = re[r]; imT[k * 8 + r] = im[r]; }
    }
    __syncthreads();
    // amp/phase on ALL 256 threads (~3.2 transcendental pairs each vs 8 on 101 threads);
    // values bitwise-identical to the owner-thread version (same inputs, same ops)
    for (int e = tid; e < FREQ * 8; e += 256) {
        double c = reT[e], sn = imT[e];
        reS[e] = sqrt(c * c + sn * sn);
        imS[e] = atan2(sn, c);
    }
    __syncthreads();

    // projection: d = tid&63; which = amp/phase; grp splits the kk range 51/50 (r11-validated)
    const int d = tid & 63, which = (tid >> 6) & 1, grp = tid >> 7;
    const float*  proj = which ? projP : projA;
    const double* src  = which ? imS : reS;         // [k][r], k-major
    double acc[8];
#pragma unroll
    for (int r = 0; r < 8; ++r) acc[r] = 0.0;
    const int kkA = grp ? 51 : 0;
    const int kkB = grp ? FREQ : 51;
    for (int kk = kkA; kk < kkB; ++kk) {
        double p = (double)proj[kk * VQD + d];
#pragma unroll
        for (int r = 0; r < 8; ++r) acc[r] += src[kk * 8 + r] * p;
    }
    if (grp) {
#pragma unroll
        for (int r = 0; r < 8; ++r) accS[(tid & 127) * 8 + r] = acc[r];
    }
    __syncthreads();
    if (grp == 0) {
#pragma unroll
        for (int r = 0; r < 8; ++r) acc[r] += accS[tid * 8 + r];
#pragma unroll
        for (int r = 0; r < 8; ++r) {
            size_t rowi = (size_t)which * ROWS + r0 + r;
            float vf = (float)acc[r];
            unsigned short hb = f2bf(vf);
            unsigned short lb = f2bf(vf - bf2f(hb));
            ftH[rowi * VQD + d] = hb;
            ftL[rowi * VQD + d] = lb;
            featD[rowi * VQD + d] = acc[r];
        }
    }
}

// ---------------- 2. bf16x3 MFMA sim + top-2, DMA double-buffered prefetch ----------------
// (round-10 version, byte-identical: best measured; argmax is closed at ~154 us — MFMA
// pipe at the bf16x3 algorithmic floor, selection VALU near op-count floor, residual
// idle resisted 4 structural attacks)
#define MFMA(a, b, c) __builtin_amdgcn_mfma_f32_16x16x32_bf16(a, b, c, 0, 0, 0)
#define UPD(val, s) do { float _v = (val); \
    bool _c1 = _v > b1v[s]; bool _c2 = _v > b2v[s]; \
    b2v[s] = _c1 ? b1v[s] : (_c2 ? _v : b2v[s]); \
    b2i[s] = _c1 ? b1i[s] : (_c2 ? idx : b2i[s]); \
    b1v[s] = _c1 ? _v : b1v[s]; \
    b1i[s] = _c1 ? idx : b1i[s]; } while (0)

__global__ __launch_bounds__(256, 3) void argmax_kernel(
    const unsigned short* __restrict__ ftH, const unsigned short* __restrict__ ftL,
    const unsigned short* __restrict__ cbH, const unsigned short* __restrict__ cbL,
    int* __restrict__ pi1, int* __restrict__ pi2)
{
    __shared__ __align__(16) char lds[33792];
    const int tid = threadIdx.x;
    const int f = blockIdx.y, z = blockIdx.z;
    const int r0 = blockIdx.x * 128;
    const int w = tid >> 6, lane = tid & 63;
    const int q = lane >> 4, cl = lane & 15;

    const unsigned short* ftHb = ftH + (size_t)f * ROWS * VQD;
    const unsigned short* ftLb = ftL + (size_t)f * ROWS * VQD;
    const unsigned short* cbHb = cbH + (size_t)f * NEMB * VQD;
    const unsigned short* cbLb = cbL + (size_t)f * NEMB * VQD;

    short8 aH00, aH01, aH10, aH11, aL00, aL01, aL10, aL11;
    {
        const size_t baseA = (size_t)(r0 + w * 32 + cl) * VQD + q * 8;
        const size_t baseB = baseA + (size_t)16 * VQD;
        aH00 = *(const short8*)(ftHb + baseA);
        aH01 = *(const short8*)(ftHb + baseA + 32);
        aH10 = *(const short8*)(ftHb + baseB);
        aH11 = *(const short8*)(ftHb + baseB + 32);
        aL00 = *(const short8*)(ftLb + baseA);
        aL01 = *(const short8*)(ftLb + baseA + 32);
        aL10 = *(const short8*)(ftLb + baseB);
        aL11 = *(const short8*)(ftLb + baseB + 32);
    }

    float b1v[8], b2v[8]; int b1i[8], b2i[8];
#pragma unroll
    for (int s = 0; s < 8; ++s) { b1v[s] = -INFINITY; b2v[s] = -INFINITY; b1i[s] = 0; b2i[s] = 0; }

    const int cBase = tid >> 3;
    const int jel   = (((tid & 7) ^ (cBase & 7)) << 3);
    const unsigned short* gH = cbHb + (size_t)(z * 2048 + cBase) * VQD + jel;
    const unsigned short* gL = cbLb + (size_t)(z * 2048 + cBase) * VQD + jel;

    const int p0 = ((q ^ (cl & 7)) << 4);
    const int p1 = p0 ^ 64;

#pragma unroll
    for (int r = 0; r < 2; ++r) {
        const size_t gofs = (size_t)(32 * r) * VQD;
        GLOAD_LDS(gH + gofs, lds + w * 1024 + r * 4096);
        GLOAD_LDS(gL + gofs, lds + 8192 + w * 1024 + r * 4096);
    }

    for (int it = 0; it < 32; ++it) {
        __syncthreads();
        if (it < 31) {
            char* nbuf = lds + ((it + 1) & 1) * 16384;
            const size_t gbase = (size_t)((it + 1) * 64) * VQD;
#pragma unroll
            for (int r = 0; r < 2; ++r) {
                const size_t gofs = gbase + (size_t)(32 * r) * VQD;
                GLOAD_LDS(gH + gofs, nbuf + w * 1024 + r * 4096);
                GLOAD_LDS(gL + gofs, nbuf + 8192 + w * 1024 + r * 4096);
            }
        }

        const char* buf = lds + (it & 1) * 16384;
        const int cbase = z * 2048 + it * 64;
#pragma unroll
        for (int nt = 0; nt < 4; ++nt) {
            const char* row = buf + (nt * 16 + cl) * 128;
            short8 bH0 = *(const short8*)(row + p0);
            short8 bH1 = *(const short8*)(row + p1);
            short8 bL0 = *(const short8*)(row + 8192 + p0);
            short8 bL1 = *(const short8*)(row + 8192 + p1);

            floatx4 acc0 = {0.f, 0.f, 0.f, 0.f};
            floatx4 acc1 = {0.f, 0.f, 0.f, 0.f};
            acc0 = MFMA(aH00, bH0, acc0);  acc1 = MFMA(aH10, bH0, acc1);
            acc0 = MFMA(aH01, bH1, acc0);  acc1 = MFMA(aH11, bH1, acc1);
            acc0 = MFMA(aH00, bL0, acc0);  acc1 = MFMA(aH10, bL0, acc1);
            acc0 = MFMA(aH01, bL1, acc0);  acc1 = MFMA(aH11, bL1, acc1);
            acc0 = MFMA(aL00, bH0, acc0);  acc1 = MFMA(aL10, bH0, acc1);
            acc0 = MFMA(aL01, bH1, acc0);  acc1 = MFMA(aL11, bH1, acc1);

            const int idx = cbase + nt * 16 + cl;
#pragma unroll
            for (int i = 0; i < 4; ++i) { UPD(acc0[i], i); UPD(acc1[i], 4 + i); }
        }
    }

    __syncthreads();
    float* redv = (float*)lds;           // [128][33]
    int*   redi = (int*)(lds + 128 * 33 * 4);
#pragma unroll
    for (int s = 0; s < 8; ++s) {
        int rowl = w * 32 + ((s & 4) << 2) + q * 4 + (s & 3);   // +16 when s>=4
        int base = rowl * 33 + cl * 2;
        redv[base]     = b1v[s]; redi[base]     = b1i[s];
        redv[base + 1] = b2v[s]; redi[base + 1] = b2i[s];
    }
    __syncthreads();
    if (tid < 128) {
        float v1 = -INFINITY, v2 = -INFINITY; int i1 = 0x7fffffff, i2 = 0x7fffffff;
        for (int e = 0; e < 32; ++e) {
            float v = redv[tid * 33 + e]; int id = redi[tid * 33 + e];
            if (v > v1 || (v == v1 && id < i1)) { v2 = v1; i2 = i1; v1 = v; i1 = id; }
            else if (v > v2 || (v == v2 && id < i2)) { v2 = v; i2 = id; }
        }
        size_t p = ((size_t)(f * 4 + z)) * ROWS + r0 + tid;
        pi1[p] = i1; pi2[p] = i2;
    }
}

// ---------------- 3. f64 rescore of the 8 candidates/row (round-5 version) ----------------
__global__ __launch_bounds__(256) void rescore_kernel(
    const double* __restrict__ featD, const double* __restrict__ invnD,
    const float* __restrict__ cbA, const float* __restrict__ cbP,
    const int* __restrict__ pi1, const int* __restrict__ pi2,
    int* __restrict__ out)
{
    const int tid = threadIdx.x;
    const int lane = tid & 63, wave = tid >> 6;
    const int task = blockIdx.x * 4 + wave;           // 0 .. 2*ROWS-1
    const int f = task / ROWS;
    const int row = task - f * ROWS;
    const float* cb = f ? cbP : cbA;
    const double fd = featD[((size_t)f * ROWS + row) * VQD + lane];

    int idxs[8];
#pragma unroll
    for (int c = 0; c < 8; ++c) {
        int zz = c >> 1;
        size_t p = ((size_t)(f * 4 + zz)) * ROWS + row;
        idxs[c] = (c & 1) ? pi2[p] : pi1[p];
    }
    double cv[8];
#pragma unroll
    for (int c = 0; c < 8; ++c)
        cv[c] = (double)cb[(size_t)idxs[c] * VQD + lane];

    double bestv = -1.0e300; int besti = 0x7fffffff;
#pragma unroll
    for (int c = 0; c < 8; ++c) {
        double t = fd * cv[c];
        for (int m = 32; m >= 1; m >>= 1) t += __shfl_xor(t, m, 64);
        double sim = t * invnD[(size_t)f * NEMB + idxs[c]];
        int idx = idxs[c];
        if (sim > bestv || (sim == bestv && idx < besti)) { bestv = sim; besti = idx; }
    }
    if (lane == 0) out[task] = besti;
}

// ---------------- launch ----------------
extern "C" void kernel_launch(void* const* d_in, const int* in_sizes, int n_in,
                              void* d_out, int out_size, void* d_ws, size_t ws_size,
                              hipStream_t stream)
{
    const float* x     = (const float*)d_in[0];
    const float* projA = (const float*)d_in[1];
    const float* projP = (const float*)d_in[2];
    const float* cbA   = (const float*)d_in[3];
    const float* cbP   = (const float*)d_in[4];

    char* ws = (char*)d_ws;
    unsigned short* ftH   = (unsigned short*)(ws + OFF_FTH);
    unsigned short* ftL   = (unsigned short*)(ws + OFF_FTL);
    unsigned short* cbHp  = (unsigned short*)(ws + OFF_CBH);
    unsigned short* cbLp  = (unsigned short*)(ws + OFF_CBL);
    double*         featD = (double*)(ws + OFF_FD);
    double*         invnD = (double*)(ws + OFF_INV);
    int*            pi1   = (int*)(ws + OFF_PI1);
    int*            pi2   = (int*)(ws + OFF_PI2);

    dft_cb_kernel<<<DFT_BLOCKS + 256, 256, 0, stream>>>(
        x, projA, projP, cbA, cbP, ftH, ftL, featD, cbHp, cbLp, invnD);
    argmax_kernel<<<dim3(ROWS / 128, 2, 4), 256, 0, stream>>>(ftH, ftL, cbHp, cbLp, pi1, pi2);
    rescore_kernel<<<(2 * ROWS) / 4, 256, 0, stream>>>(featD, invnD, cbA, cbP, pi1, pi2, (int*)d_out);
}